// Round 2
// baseline (3148.786 us; speedup 1.0000x reference)
//
#include <hip/hip_runtime.h>
#include <cstddef>

#define NN 100000
#define HH 128
#define H2C 64
#define EE 800000

// ---------------- helpers ----------------

__device__ __forceinline__ void atomic_add_f(float* p, float v){
  unsafeAtomicAdd(p, v);  // hardware global_atomic_add_f32 on gfx950
}

__device__ __forceinline__ float gelu_f(float v){
  return 0.5f * v * (1.0f + erff(v * 0.70710678118654752f));
}

__device__ __forceinline__ float red16(float s){
  s += __shfl_xor(s, 1);
  s += __shfl_xor(s, 2);
  s += __shfl_xor(s, 4);
  s += __shfl_xor(s, 8);
  return s;
}

// Stage a 64-node x 64-k chunk of A into As[64][68] (pad 4 -> conflict-free reads).
// src rows are 128 floats; col_off selects which 64-column slice; optional per-node scale.
__device__ __forceinline__ void stage_A(float* As, const float* __restrict__ src,
                                        const float* __restrict__ scale,
                                        int node_base, int col_off){
  const int t = threadIdx.x;
  #pragma unroll
  for (int i = 0; i < 4; ++i){
    int idx4 = t + i * 256;          // 1024 float4 total
    int m  = idx4 >> 4;              // node within tile
    int k4 = idx4 & 15;              // float4 within 64-k slice
    int node = node_base + m;
    float4 v = make_float4(0.f, 0.f, 0.f, 0.f);
    if (node < NN){
      v = *(const float4*)(src + (size_t)node * HH + col_off + (k4 << 2));
      if (scale){ float s = scale[node]; v.x *= s; v.y *= s; v.z *= s; v.w *= s; }
    }
    *(float4*)(As + m * 68 + (k4 << 2)) = v;
  }
}

// Copy a packed k-major weight chunk into Bs.
__device__ __forceinline__ void stage_B(float* Bs, const float* __restrict__ src, int nfloat4){
  for (int idx4 = threadIdx.x; idx4 < nfloat4; idx4 += 256){
    *(float4*)(Bs + (idx4 << 2)) = *(const float4*)(src + (idx4 << 2));
  }
}

// 64-wide B (single output quad), accumulate into acc[4][4]
__device__ __forceinline__ void gemm64(const float* As, const float* Bs,
                                       float (*acc)[4], int mb, int jq){
  #pragma unroll 8
  for (int k = 0; k < 64; ++k){
    float4 bq = *(const float4*)(Bs + (k << 6) + jq);
    float a0 = As[(mb + 0) * 68 + k];
    float a1 = As[(mb + 1) * 68 + k];
    float a2 = As[(mb + 2) * 68 + k];
    float a3 = As[(mb + 3) * 68 + k];
    acc[0][0] += a0 * bq.x; acc[0][1] += a0 * bq.y; acc[0][2] += a0 * bq.z; acc[0][3] += a0 * bq.w;
    acc[1][0] += a1 * bq.x; acc[1][1] += a1 * bq.y; acc[1][2] += a1 * bq.z; acc[1][3] += a1 * bq.w;
    acc[2][0] += a2 * bq.x; acc[2][1] += a2 * bq.y; acc[2][2] += a2 * bq.z; acc[2][3] += a2 * bq.w;
    acc[3][0] += a3 * bq.x; acc[3][1] += a3 * bq.y; acc[3][2] += a3 * bq.z; acc[3][3] += a3 * bq.w;
  }
}

// 128-wide B (both quads), accumulate into accP/accN
__device__ __forceinline__ void gemm128(const float* As, const float* Bs,
                                        float (*accP)[4], float (*accN)[4], int mb, int jq){
  #pragma unroll 4
  for (int k = 0; k < 64; ++k){
    float4 bp = *(const float4*)(Bs + (k << 7) + jq);
    float4 bn = *(const float4*)(Bs + (k << 7) + 64 + jq);
    float a0 = As[(mb + 0) * 68 + k];
    float a1 = As[(mb + 1) * 68 + k];
    float a2 = As[(mb + 2) * 68 + k];
    float a3 = As[(mb + 3) * 68 + k];
    accP[0][0] += a0 * bp.x; accP[0][1] += a0 * bp.y; accP[0][2] += a0 * bp.z; accP[0][3] += a0 * bp.w;
    accP[1][0] += a1 * bp.x; accP[1][1] += a1 * bp.y; accP[1][2] += a1 * bp.z; accP[1][3] += a1 * bp.w;
    accP[2][0] += a2 * bp.x; accP[2][1] += a2 * bp.y; accP[2][2] += a2 * bp.z; accP[2][3] += a2 * bp.w;
    accP[3][0] += a3 * bp.x; accP[3][1] += a3 * bp.y; accP[3][2] += a3 * bp.z; accP[3][3] += a3 * bp.w;
    accN[0][0] += a0 * bn.x; accN[0][1] += a0 * bn.y; accN[0][2] += a0 * bn.z; accN[0][3] += a0 * bn.w;
    accN[1][0] += a1 * bn.x; accN[1][1] += a1 * bn.y; accN[1][2] += a1 * bn.z; accN[1][3] += a1 * bn.w;
    accN[2][0] += a2 * bn.x; accN[2][1] += a2 * bn.y; accN[2][2] += a2 * bn.z; accN[2][3] += a2 * bn.w;
    accN[3][0] += a3 * bn.x; accN[3][1] += a3 * bn.y; accN[3][2] += a3 * bn.z; accN[3][3] += a3 * bn.w;
  }
}

// GEMM with A = T in LDS laid out [64][132], k offset kk
__device__ __forceinline__ void gemmT(const float* T, const float* Bs,
                                      float (*accP)[4], float (*accN)[4], int mb, int jq, int kk){
  #pragma unroll 4
  for (int k = 0; k < 64; ++k){
    float4 bp = *(const float4*)(Bs + (k << 7) + jq);
    float4 bn = *(const float4*)(Bs + (k << 7) + 64 + jq);
    float a0 = T[(mb + 0) * 132 + kk + k];
    float a1 = T[(mb + 1) * 132 + kk + k];
    float a2 = T[(mb + 2) * 132 + kk + k];
    float a3 = T[(mb + 3) * 132 + kk + k];
    accP[0][0] += a0 * bp.x; accP[0][1] += a0 * bp.y; accP[0][2] += a0 * bp.z; accP[0][3] += a0 * bp.w;
    accP[1][0] += a1 * bp.x; accP[1][1] += a1 * bp.y; accP[1][2] += a1 * bp.z; accP[1][3] += a1 * bp.w;
    accP[2][0] += a2 * bp.x; accP[2][1] += a2 * bp.y; accP[2][2] += a2 * bp.z; accP[2][3] += a2 * bp.w;
    accP[3][0] += a3 * bp.x; accP[3][1] += a3 * bp.y; accP[3][2] += a3 * bp.z; accP[3][3] += a3 * bp.w;
    accN[0][0] += a0 * bn.x; accN[0][1] += a0 * bn.y; accN[0][2] += a0 * bn.z; accN[0][3] += a0 * bn.w;
    accN[1][0] += a1 * bn.x; accN[1][1] += a1 * bn.y; accN[1][2] += a1 * bn.z; accN[1][3] += a1 * bn.w;
    accN[2][0] += a2 * bn.x; accN[2][1] += a2 * bn.y; accN[2][2] += a2 * bn.z; accN[2][3] += a2 * bn.w;
    accN[3][0] += a3 * bn.x; accN[3][1] += a3 * bn.y; accN[3][2] += a3 * bn.z; accN[3][3] += a3 * bn.w;
  }
}

// relu + LayerNorm epilogue; values for one node row live in 16 consecutive lanes.
__device__ __forceinline__ void ln_epilogue(float (*accP)[4], float (*accN)[4],
    const float* __restrict__ biasP, const float* __restrict__ biasN,
    const float* __restrict__ g, const float* __restrict__ b,
    float* __restrict__ out, int node_base, int mb, int jq)
{
  float4 bp  = *(const float4*)(biasP + jq);
  float4 bn  = *(const float4*)(biasN + jq);
  float4 gp  = *(const float4*)(g + jq);
  float4 gn  = *(const float4*)(g + 64 + jq);
  float4 b0p = *(const float4*)(b + jq);
  float4 b0n = *(const float4*)(b + 64 + jq);
  #pragma unroll
  for (int i = 0; i < 4; ++i){
    int node = node_base + mb + i;
    float v0 = fmaxf(accP[i][0] + bp.x, 0.f);
    float v1 = fmaxf(accP[i][1] + bp.y, 0.f);
    float v2 = fmaxf(accP[i][2] + bp.z, 0.f);
    float v3 = fmaxf(accP[i][3] + bp.w, 0.f);
    float v4 = fmaxf(accN[i][0] + bn.x, 0.f);
    float v5 = fmaxf(accN[i][1] + bn.y, 0.f);
    float v6 = fmaxf(accN[i][2] + bn.z, 0.f);
    float v7 = fmaxf(accN[i][3] + bn.w, 0.f);
    float s = v0 + v1 + v2 + v3 + v4 + v5 + v6 + v7;
    s = red16(s);
    float mu = s * (1.0f / 128.0f);
    float d0 = v0 - mu, d1 = v1 - mu, d2 = v2 - mu, d3 = v3 - mu;
    float d4 = v4 - mu, d5 = v5 - mu, d6 = v6 - mu, d7 = v7 - mu;
    float q = d0*d0 + d1*d1 + d2*d2 + d3*d3 + d4*d4 + d5*d5 + d6*d6 + d7*d7;
    q = red16(q);
    float rstd = rsqrtf(q * (1.0f / 128.0f) + 1e-5f);
    if (node < NN){
      float4 o;
      o.x = d0 * rstd * gp.x + b0p.x;
      o.y = d1 * rstd * gp.y + b0p.y;
      o.z = d2 * rstd * gp.z + b0p.z;
      o.w = d3 * rstd * gp.w + b0p.w;
      *(float4*)(out + (size_t)node * HH + jq) = o;
      o.x = d4 * rstd * gn.x + b0n.x;
      o.y = d5 * rstd * gn.y + b0n.y;
      o.z = d6 * rstd * gn.z + b0n.z;
      o.w = d7 * rstd * gn.w + b0n.w;
      *(float4*)(out + (size_t)node * HH + 64 + jq) = o;
    }
  }
}

// ---------------- kernels ----------------

// Transpose/pack all weights into k-major form (offsets in floats documented inline).
__global__ void prep_kernel(const float* __restrict__ c0_pl, const float* __restrict__ c0_pr,
                            const float* __restrict__ c0_nl, const float* __restrict__ c0_nr,
                            const float* __restrict__ c1_pl, const float* __restrict__ c1_pr,
                            const float* __restrict__ c1_nl, const float* __restrict__ c1_nr,
                            const float* __restrict__ pw1, const float* __restrict__ pw2,
                            float* __restrict__ WT){
  int t = blockIdx.x * 256 + threadIdx.x;
  if (t >= 90112) return;
  if (t < 8192){                       // WT0pl [128][64] = c0_pl^T
    int k = t >> 6, j = t & 63; WT[t] = c0_pl[j * 128 + k];
  } else if (t < 16384){               // WT0nl
    int u = t - 8192; int k = u >> 6, j = u & 63; WT[t] = c0_nl[j * 128 + k];
  } else if (t < 32768){               // WT0r [128][128] = [c0_pr^T | c0_nr^T]
    int u = t - 16384; int k = u >> 7, j = u & 127;
    WT[t] = (j < 64) ? c0_pr[j * 128 + k] : c0_nr[(j - 64) * 128 + k];
  } else if (t < 36864){               // P1 = c1_pl[:, :64]^T
    int u = t - 32768; int k = u >> 6, j = u & 63; WT[t] = c1_pl[j * 128 + k];
  } else if (t < 40960){               // P2 = c1_nl[:, :64]^T
    int u = t - 36864; int k = u >> 6, j = u & 63; WT[t] = c1_nl[j * 128 + k];
  } else if (t < 45056){               // P3 = c1_nl[:, 64:]^T
    int u = t - 40960; int k = u >> 6, j = u & 63; WT[t] = c1_nl[j * 128 + 64 + k];
  } else if (t < 49152){               // P4 = c1_pl[:, 64:]^T
    int u = t - 45056; int k = u >> 6, j = u & 63; WT[t] = c1_pl[j * 128 + 64 + k];
  } else if (t < 53248){               // P5 = c1_pr^T (64x64)
    int u = t - 49152; int k = u >> 6, j = u & 63; WT[t] = c1_pr[j * 64 + k];
  } else if (t < 57344){               // P6 = c1_nr^T (64x64)
    int u = t - 53248; int k = u >> 6, j = u & 63; WT[t] = c1_nr[j * 64 + k];
  } else if (t < 73728){               // WTp1 = pw1^T [128][128]
    int u = t - 57344; int k = u >> 7, j = u & 127; WT[t] = pw1[j * 128 + k];
  } else {                             // WTp2 = pw2^T
    int u = t - 73728; int k = u >> 7, j = u & 127; WT[t] = pw2[j * 128 + k];
  }
}

__global__ void count_kernel(const int* __restrict__ pe, const int* __restrict__ ne,
                             float* __restrict__ cp, float* __restrict__ cn){
  int t = blockIdx.x * 256 + threadIdx.x;
  if (t < EE)            atomic_add_f(&cp[pe[EE + t]], 1.0f);
  else if (t < 2 * EE)   atomic_add_f(&cn[ne[EE + (t - EE)]], 1.0f);
}

__global__ void rcp_kernel(float* __restrict__ cp, float* __restrict__ cn){
  int i = blockIdx.x * 256 + threadIdx.x;
  if (i < NN){
    cp[i] = 1.0f / fmaxf(cp[i], 1.0f);
    cn[i] = 1.0f / fmaxf(cn[i], 1.0f);
  }
}

// One wave per edge; lane handles 2 features (float2 gather + 2 f32 atomics).
__global__ void agg_kernel(const float* __restrict__ feat,
                           const int* __restrict__ pe, const int* __restrict__ ne,
                           float* __restrict__ sp, float* __restrict__ sn){
  int wid  = (blockIdx.x * 256 + threadIdx.x) >> 6;
  int lane = threadIdx.x & 63;
  const int* eptr; float* outp; int e;
  if (wid < EE){ e = wid;      eptr = pe; outp = sp; }
  else         { e = wid - EE; eptr = ne; outp = sn; }
  int src = eptr[e];
  int dst = eptr[EE + e];
  float2 v = *(const float2*)(feat + (size_t)src * HH + lane * 2);
  atomic_add_f(outp + (size_t)dst * HH + lane * 2,     v.x);
  atomic_add_f(outp + (size_t)dst * HH + lane * 2 + 1, v.y);
}

__global__ __launch_bounds__(256) void l0_kernel(
    const float* __restrict__ x, const float* __restrict__ sp, const float* __restrict__ sn,
    const float* __restrict__ rp, const float* __restrict__ rn,
    const float* __restrict__ WT,
    const float* __restrict__ biasP, const float* __restrict__ biasN,
    const float* __restrict__ lng, const float* __restrict__ lnb,
    float* __restrict__ h0)
{
  __shared__ float smem[4352 + 8192];
  float* As = smem; float* Bs = smem + 4352;
  const int node_base = blockIdx.x << 6;
  const int jq = (threadIdx.x & 15) << 2;
  const int mb = (threadIdx.x >> 4) << 2;
  float accP[4][4] = {}; float accN[4][4] = {};

  // phase 1: ap @ c0_pl^T  (POS)
  #pragma unroll
  for (int kk = 0; kk < 128; kk += 64){
    __syncthreads();
    stage_A(As, sp, rp, node_base, kk);
    stage_B(Bs, WT + 0 + kk * 64, 1024);
    __syncthreads();
    gemm64(As, Bs, accP, mb, jq);
  }
  // phase 2: an @ c0_nl^T  (NEG)
  #pragma unroll
  for (int kk = 0; kk < 128; kk += 64){
    __syncthreads();
    stage_A(As, sn, rn, node_base, kk);
    stage_B(Bs, WT + 8192 + kk * 64, 1024);
    __syncthreads();
    gemm64(As, Bs, accN, mb, jq);
  }
  // phase 3: x @ [c0_pr^T | c0_nr^T]  (BOTH)
  #pragma unroll
  for (int kk = 0; kk < 128; kk += 64){
    __syncthreads();
    stage_A(As, x, nullptr, node_base, kk);
    stage_B(Bs, WT + 16384 + kk * 128, 2048);
    __syncthreads();
    gemm128(As, Bs, accP, accN, mb, jq);
  }
  ln_epilogue(accP, accN, biasP, biasN, lng, lnb, h0, node_base, mb, jq);
}

__global__ __launch_bounds__(256) void l1_kernel(
    const float* __restrict__ h0, const float* __restrict__ sp, const float* __restrict__ sn,
    const float* __restrict__ rp, const float* __restrict__ rn,
    const float* __restrict__ WT,
    const float* __restrict__ biasP, const float* __restrict__ biasN,
    const float* __restrict__ lng, const float* __restrict__ lnb,
    float* __restrict__ h1)
{
  __shared__ float smem[4352 + 8192];
  float* As = smem; float* Bs = smem + 4352;
  const int node_base = blockIdx.x << 6;
  const int jq = (threadIdx.x & 15) << 2;
  const int mb = (threadIdx.x >> 4) << 2;
  float accP[4][4] = {}; float accN[4][4] = {};

  // ph1: P[0:64]  -> POS  (B = c1_pl[:, :64]^T)
  __syncthreads(); stage_A(As, sp, rp, node_base, 0);  stage_B(Bs, WT + 32768, 1024);
  __syncthreads(); gemm64(As, Bs, accP, mb, jq);
  // ph2: P[64:]   -> NEG  (B = c1_nl[:, :64]^T)
  __syncthreads(); stage_A(As, sp, rp, node_base, 64); stage_B(Bs, WT + 36864, 1024);
  __syncthreads(); gemm64(As, Bs, accN, mb, jq);
  // ph3: Q[0:64]  -> NEG  (B = c1_nl[:, 64:]^T)
  __syncthreads(); stage_A(As, sn, rn, node_base, 0);  stage_B(Bs, WT + 40960, 1024);
  __syncthreads(); gemm64(As, Bs, accN, mb, jq);
  // ph4: Q[64:]   -> POS  (B = c1_pl[:, 64:]^T)
  __syncthreads(); stage_A(As, sn, rn, node_base, 64); stage_B(Bs, WT + 45056, 1024);
  __syncthreads(); gemm64(As, Bs, accP, mb, jq);
  // ph5: xp       -> POS  (B = c1_pr^T)
  __syncthreads(); stage_A(As, h0, nullptr, node_base, 0);  stage_B(Bs, WT + 49152, 1024);
  __syncthreads(); gemm64(As, Bs, accP, mb, jq);
  // ph6: xn       -> NEG  (B = c1_nr^T)
  __syncthreads(); stage_A(As, h0, nullptr, node_base, 64); stage_B(Bs, WT + 53248, 1024);
  __syncthreads(); gemm64(As, Bs, accN, mb, jq);

  ln_epilogue(accP, accN, biasP, biasN, lng, lnb, h1, node_base, mb, jq);
}

__global__ __launch_bounds__(256) void mlp_kernel(
    const float* __restrict__ h1, const float* __restrict__ x0,
    const float* __restrict__ WT, const float* __restrict__ pb1, const float* __restrict__ pb2,
    const float* __restrict__ gate, float* __restrict__ out)
{
  __shared__ float smem[8448 + 8192];
  float* As = smem;            // [64][68] during GEMM1
  float* T  = smem;            // [64][132] afterwards (overlaps As; dead by then)
  float* Bs = smem + 8448;
  const int node_base = blockIdx.x << 6;
  const int jq = (threadIdx.x & 15) << 2;
  const int mb = (threadIdx.x >> 4) << 2;
  float accP[4][4] = {}; float accN[4][4] = {};

  #pragma unroll
  for (int kk = 0; kk < 128; kk += 64){
    __syncthreads();
    stage_A(As, h1, nullptr, node_base, kk);
    stage_B(Bs, WT + 57344 + kk * 128, 2048);
    __syncthreads();
    gemm128(As, Bs, accP, accN, mb, jq);
  }
  __syncthreads();  // everyone done reading As before T overwrites it
  {
    float4 p1p = *(const float4*)(pb1 + jq);
    float4 p1n = *(const float4*)(pb1 + 64 + jq);
    #pragma unroll
    for (int i = 0; i < 4; ++i){
      float4 tp, tn;
      tp.x = gelu_f(accP[i][0] + p1p.x);
      tp.y = gelu_f(accP[i][1] + p1p.y);
      tp.z = gelu_f(accP[i][2] + p1p.z);
      tp.w = gelu_f(accP[i][3] + p1p.w);
      tn.x = gelu_f(accN[i][0] + p1n.x);
      tn.y = gelu_f(accN[i][1] + p1n.y);
      tn.z = gelu_f(accN[i][2] + p1n.z);
      tn.w = gelu_f(accN[i][3] + p1n.w);
      *(float4*)(T + (mb + i) * 132 + jq) = tp;
      *(float4*)(T + (mb + i) * 132 + 64 + jq) = tn;
    }
  }
  #pragma unroll
  for (int i = 0; i < 4; ++i)
    #pragma unroll
    for (int q = 0; q < 4; ++q){ accP[i][q] = 0.f; accN[i][q] = 0.f; }

  #pragma unroll
  for (int kk = 0; kk < 128; kk += 64){
    __syncthreads();               // first iter: T writes visible to all
    stage_B(Bs, WT + 73728 + kk * 128, 2048);
    __syncthreads();
    gemmT(T, Bs, accP, accN, mb, jq, kk);
  }

  float gt = gate[0], og = 1.0f - gt;
  float4 p2p = *(const float4*)(pb2 + jq);
  float4 p2n = *(const float4*)(pb2 + 64 + jq);
  #pragma unroll
  for (int i = 0; i < 4; ++i){
    int node = node_base + mb + i;
    if (node < NN){
      float4 xr = *(const float4*)(x0 + (size_t)node * HH + jq);
      float4 o;
      o.x = gt * (accP[i][0] + p2p.x) + og * xr.x;
      o.y = gt * (accP[i][1] + p2p.y) + og * xr.y;
      o.z = gt * (accP[i][2] + p2p.z) + og * xr.z;
      o.w = gt * (accP[i][3] + p2p.w) + og * xr.w;
      *(float4*)(out + (size_t)node * HH + jq) = o;
      xr = *(const float4*)(x0 + (size_t)node * HH + 64 + jq);
      o.x = gt * (accN[i][0] + p2n.x) + og * xr.x;
      o.y = gt * (accN[i][1] + p2n.y) + og * xr.y;
      o.z = gt * (accN[i][2] + p2n.z) + og * xr.z;
      o.w = gt * (accN[i][3] + p2n.w) + og * xr.w;
      *(float4*)(out + (size_t)node * HH + 64 + jq) = o;
    }
  }
}

// ---------------- launch ----------------

extern "C" void kernel_launch(void* const* d_in, const int* in_sizes, int n_in,
                              void* d_out, int out_size, void* d_ws, size_t ws_size,
                              hipStream_t stream){
  (void)in_sizes; (void)n_in; (void)out_size;
  const float* x     = (const float*)d_in[0];
  const int*   pe    = (const int*)d_in[1];
  const int*   ne    = (const int*)d_in[2];
  const float* c0_pl = (const float*)d_in[3];
  const float* c0_pr = (const float*)d_in[4];
  const float* c0_pr_b = (const float*)d_in[5];
  const float* c0_nl = (const float*)d_in[6];
  const float* c0_nr = (const float*)d_in[7];
  const float* c0_nr_b = (const float*)d_in[8];
  const float* c1_pl = (const float*)d_in[9];
  const float* c1_pr = (const float*)d_in[10];
  const float* c1_pr_b = (const float*)d_in[11];
  const float* c1_nl = (const float*)d_in[12];
  const float* c1_nr = (const float*)d_in[13];
  const float* c1_nr_b = (const float*)d_in[14];
  const float* ln0_g = (const float*)d_in[15];
  const float* ln0_b = (const float*)d_in[16];
  const float* ln1_g = (const float*)d_in[17];
  const float* ln1_b = (const float*)d_in[18];
  const float* pw1   = (const float*)d_in[19];
  const float* pb1   = (const float*)d_in[20];
  const float* pw2   = (const float*)d_in[21];
  const float* pb2   = (const float*)d_in[22];
  const float* gate  = (const float*)d_in[23];
  float* out = (float*)d_out;
  float* ws  = (float*)d_ws;

  // Workspace layout (floats):
  const size_t need = (size_t)3 * NN * HH + 2 * NN + 90112;
  if (ws_size < need * sizeof(float)) return;  // defensive: never scribble OOB

  float* s_pos = ws;                                   // N*128
  float* s_neg = ws + (size_t)NN * HH;                 // N*128
  float* cnt_p = ws + (size_t)2 * NN * HH;             // N (becomes rcp)
  float* cnt_n = cnt_p + NN;                           // N
  float* h0    = cnt_n + NN;                           // N*128
  float* WT    = h0 + (size_t)NN * HH;                 // 90112 floats

  // zero accumulators + counts in one shot
  hipMemsetAsync(ws, 0, ((size_t)2 * NN * HH + 2 * NN) * sizeof(float), stream);
  prep_kernel<<<352, 256, 0, stream>>>(c0_pl, c0_pr, c0_nl, c0_nr,
                                       c1_pl, c1_pr, c1_nl, c1_nr, pw1, pw2, WT);
  count_kernel<<<(2 * EE + 255) / 256, 256, 0, stream>>>(pe, ne, cnt_p, cnt_n);
  rcp_kernel<<<(NN + 255) / 256, 256, 0, stream>>>(cnt_p, cnt_n);
  agg_kernel<<<(2 * EE) / 4, 256, 0, stream>>>(x, pe, ne, s_pos, s_neg);
  l0_kernel<<<(NN + 63) / 64, 256, 0, stream>>>(x, s_pos, s_neg, cnt_p, cnt_n, WT,
                                                c0_pr_b, c0_nr_b, ln0_g, ln0_b, h0);
  hipMemsetAsync(ws, 0, (size_t)2 * NN * HH * sizeof(float), stream);
  agg_kernel<<<(2 * EE) / 4, 256, 0, stream>>>(h0, pe, ne, s_pos, s_neg);
  l1_kernel<<<(NN + 63) / 64, 256, 0, stream>>>(h0, s_pos, s_neg, cnt_p, cnt_n, WT,
                                                c1_pr_b, c1_nr_b, ln1_g, ln1_b, out);
  mlp_kernel<<<(NN + 63) / 64, 256, 0, stream>>>(out, x, WT, pb1, pb2, gate, out);
}

// Round 6
// 959.839 us; speedup vs baseline: 3.2805x; 3.2805x over previous
//
#include <hip/hip_runtime.h>
#include <cstddef>

#define NN 100000
#define HH 128
#define H2C 64
#define EE 800000

// ---------------- helpers ----------------

__device__ __forceinline__ float gelu_f(float v){
  return 0.5f * v * (1.0f + erff(v * 0.70710678118654752f));
}

__device__ __forceinline__ float red16(float s){
  s += __shfl_xor(s, 1);
  s += __shfl_xor(s, 2);
  s += __shfl_xor(s, 4);
  s += __shfl_xor(s, 8);
  return s;
}

// Stage a 64-node x 64-k chunk of A into As[64][68] (pad 4 -> conflict-free reads).
__device__ __forceinline__ void stage_A(float* As, const float* __restrict__ src,
                                        int node_base, int col_off){
  const int t = threadIdx.x;
  #pragma unroll
  for (int i = 0; i < 4; ++i){
    int idx4 = t + i * 256;          // 1024 float4 total
    int m  = idx4 >> 4;              // node within tile
    int k4 = idx4 & 15;              // float4 within 64-k slice
    int node = node_base + m;
    float4 v = make_float4(0.f, 0.f, 0.f, 0.f);
    if (node < NN){
      v = *(const float4*)(src + (size_t)node * HH + col_off + (k4 << 2));
    }
    *(float4*)(As + m * 68 + (k4 << 2)) = v;
  }
}

// Copy a packed k-major weight chunk into Bs.
__device__ __forceinline__ void stage_B(float* Bs, const float* __restrict__ src, int nfloat4){
  for (int idx4 = threadIdx.x; idx4 < nfloat4; idx4 += 256){
    *(float4*)(Bs + (idx4 << 2)) = *(const float4*)(src + (idx4 << 2));
  }
}

// 64-wide B (single output quad), accumulate into acc[4][4]
__device__ __forceinline__ void gemm64(const float* As, const float* Bs,
                                       float (*acc)[4], int mb, int jq){
  #pragma unroll 8
  for (int k = 0; k < 64; ++k){
    float4 bq = *(const float4*)(Bs + (k << 6) + jq);
    float a0 = As[(mb + 0) * 68 + k];
    float a1 = As[(mb + 1) * 68 + k];
    float a2 = As[(mb + 2) * 68 + k];
    float a3 = As[(mb + 3) * 68 + k];
    acc[0][0] += a0 * bq.x; acc[0][1] += a0 * bq.y; acc[0][2] += a0 * bq.z; acc[0][3] += a0 * bq.w;
    acc[1][0] += a1 * bq.x; acc[1][1] += a1 * bq.y; acc[1][2] += a1 * bq.z; acc[1][3] += a1 * bq.w;
    acc[2][0] += a2 * bq.x; acc[2][1] += a2 * bq.y; acc[2][2] += a2 * bq.z; acc[2][3] += a2 * bq.w;
    acc[3][0] += a3 * bq.x; acc[3][1] += a3 * bq.y; acc[3][2] += a3 * bq.z; acc[3][3] += a3 * bq.w;
  }
}

// 128-wide B (both quads), accumulate into accP/accN
__device__ __forceinline__ void gemm128(const float* As, const float* Bs,
                                        float (*accP)[4], float (*accN)[4], int mb, int jq){
  #pragma unroll 4
  for (int k = 0; k < 64; ++k){
    float4 bp = *(const float4*)(Bs + (k << 7) + jq);
    float4 bn = *(const float4*)(Bs + (k << 7) + 64 + jq);
    float a0 = As[(mb + 0) * 68 + k];
    float a1 = As[(mb + 1) * 68 + k];
    float a2 = As[(mb + 2) * 68 + k];
    float a3 = As[(mb + 3) * 68 + k];
    accP[0][0] += a0 * bp.x; accP[0][1] += a0 * bp.y; accP[0][2] += a0 * bp.z; accP[0][3] += a0 * bp.w;
    accP[1][0] += a1 * bp.x; accP[1][1] += a1 * bp.y; accP[1][2] += a1 * bp.z; accP[1][3] += a1 * bp.w;
    accP[2][0] += a2 * bp.x; accP[2][1] += a2 * bp.y; accP[2][2] += a2 * bp.z; accP[2][3] += a2 * bp.w;
    accP[3][0] += a3 * bp.x; accP[3][1] += a3 * bp.y; accP[3][2] += a3 * bp.z; accP[3][3] += a3 * bp.w;
    accN[0][0] += a0 * bn.x; accN[0][1] += a0 * bn.y; accN[0][2] += a0 * bn.z; accN[0][3] += a0 * bn.w;
    accN[1][0] += a1 * bn.x; accN[1][1] += a1 * bn.y; accN[1][2] += a1 * bn.z; accN[1][3] += a1 * bn.w;
    accN[2][0] += a2 * bn.x; accN[2][1] += a2 * bn.y; accN[2][2] += a2 * bn.z; accN[2][3] += a2 * bn.w;
    accN[3][0] += a3 * bn.x; accN[3][1] += a3 * bn.y; accN[3][2] += a3 * bn.z; accN[3][3] += a3 * bn.w;
  }
}

// GEMM with A = T in LDS laid out [64][132], k offset kk
__device__ __forceinline__ void gemmT(const float* T, const float* Bs,
                                      float (*accP)[4], float (*accN)[4], int mb, int jq, int kk){
  #pragma unroll 4
  for (int k = 0; k < 64; ++k){
    float4 bp = *(const float4*)(Bs + (k << 7) + jq);
    float4 bn = *(const float4*)(Bs + (k << 7) + 64 + jq);
    float a0 = T[(mb + 0) * 132 + kk + k];
    float a1 = T[(mb + 1) * 132 + kk + k];
    float a2 = T[(mb + 2) * 132 + kk + k];
    float a3 = T[(mb + 3) * 132 + kk + k];
    accP[0][0] += a0 * bp.x; accP[0][1] += a0 * bp.y; accP[0][2] += a0 * bp.z; accP[0][3] += a0 * bp.w;
    accP[1][0] += a1 * bp.x; accP[1][1] += a1 * bp.y; accP[1][2] += a1 * bp.z; accP[1][3] += a1 * bp.w;
    accP[2][0] += a2 * bp.x; accP[2][1] += a2 * bp.y; accP[2][2] += a2 * bp.z; accP[2][3] += a2 * bp.w;
    accP[3][0] += a3 * bp.x; accP[3][1] += a3 * bp.y; accP[3][2] += a3 * bp.z; accP[3][3] += a3 * bp.w;
    accN[0][0] += a0 * bn.x; accN[0][1] += a0 * bn.y; accN[0][2] += a0 * bn.z; accN[0][3] += a0 * bn.w;
    accN[1][0] += a1 * bn.x; accN[1][1] += a1 * bn.y; accN[1][2] += a1 * bn.z; accN[1][3] += a1 * bn.w;
    accN[2][0] += a2 * bn.x; accN[2][1] += a2 * bn.y; accN[2][2] += a2 * bn.z; accN[2][3] += a2 * bn.w;
    accN[3][0] += a3 * bn.x; accN[3][1] += a3 * bn.y; accN[3][2] += a3 * bn.z; accN[3][3] += a3 * bn.w;
  }
}

// relu + LayerNorm epilogue; values for one node row live in 16 consecutive lanes.
__device__ __forceinline__ void ln_epilogue(float (*accP)[4], float (*accN)[4],
    const float* __restrict__ biasP, const float* __restrict__ biasN,
    const float* __restrict__ g, const float* __restrict__ b,
    float* __restrict__ out, int node_base, int mb, int jq)
{
  float4 bp  = *(const float4*)(biasP + jq);
  float4 bn  = *(const float4*)(biasN + jq);
  float4 gp  = *(const float4*)(g + jq);
  float4 gn  = *(const float4*)(g + 64 + jq);
  float4 b0p = *(const float4*)(b + jq);
  float4 b0n = *(const float4*)(b + 64 + jq);
  #pragma unroll
  for (int i = 0; i < 4; ++i){
    int node = node_base + mb + i;
    float v0 = fmaxf(accP[i][0] + bp.x, 0.f);
    float v1 = fmaxf(accP[i][1] + bp.y, 0.f);
    float v2 = fmaxf(accP[i][2] + bp.z, 0.f);
    float v3 = fmaxf(accP[i][3] + bp.w, 0.f);
    float v4 = fmaxf(accN[i][0] + bn.x, 0.f);
    float v5 = fmaxf(accN[i][1] + bn.y, 0.f);
    float v6 = fmaxf(accN[i][2] + bn.z, 0.f);
    float v7 = fmaxf(accN[i][3] + bn.w, 0.f);
    float s = v0 + v1 + v2 + v3 + v4 + v5 + v6 + v7;
    s = red16(s);
    float mu = s * (1.0f / 128.0f);
    float d0 = v0 - mu, d1 = v1 - mu, d2 = v2 - mu, d3 = v3 - mu;
    float d4 = v4 - mu, d5 = v5 - mu, d6 = v6 - mu, d7 = v7 - mu;
    float q = d0*d0 + d1*d1 + d2*d2 + d3*d3 + d4*d4 + d5*d5 + d6*d6 + d7*d7;
    q = red16(q);
    float rstd = rsqrtf(q * (1.0f / 128.0f) + 1e-5f);
    if (node < NN){
      float4 o;
      o.x = d0 * rstd * gp.x + b0p.x;
      o.y = d1 * rstd * gp.y + b0p.y;
      o.z = d2 * rstd * gp.z + b0p.z;
      o.w = d3 * rstd * gp.w + b0p.w;
      *(float4*)(out + (size_t)node * HH + jq) = o;
      o.x = d4 * rstd * gn.x + b0n.x;
      o.y = d5 * rstd * gn.y + b0n.y;
      o.z = d6 * rstd * gn.z + b0n.z;
      o.w = d7 * rstd * gn.w + b0n.w;
      *(float4*)(out + (size_t)node * HH + 64 + jq) = o;
    }
  }
}

// ---------------- CSR build ----------------

__global__ void hist_kernel(const int* __restrict__ pe, const int* __restrict__ ne,
                            int* __restrict__ cnt_p, int* __restrict__ cnt_n){
  int t = blockIdx.x * 256 + threadIdx.x;
  if (t < EE)            atomicAdd(&cnt_p[pe[EE + t]], 1);
  else if (t < 2 * EE)   atomicAdd(&cnt_n[ne[EE + (t - EE)]], 1);
}

// scan1: 98 blocks x 256 thr x (4 elem) per array; local exclusive prefix into off,
// block totals into parts[arr*128 + b].
__global__ void scan1_kernel(const int* __restrict__ cnt_p, const int* __restrict__ cnt_n,
                             int* __restrict__ off_p, int* __restrict__ off_n,
                             int* __restrict__ parts){
  __shared__ int sh[256];
  const int arr = blockIdx.y;
  const int* cnt = arr ? cnt_n : cnt_p;
  int* off = arr ? off_n : off_p;
  const int b = blockIdx.x, t = threadIdx.x;
  const int base = b * 1024 + t * 4;
  int4 v = make_int4(0, 0, 0, 0);
  if (base + 3 < NN) v = *(const int4*)(cnt + base);
  else {
    if (base + 0 < NN) v.x = cnt[base + 0];
    if (base + 1 < NN) v.y = cnt[base + 1];
    if (base + 2 < NN) v.z = cnt[base + 2];
  }
  int s = v.x + v.y + v.z + v.w;
  sh[t] = s; __syncthreads();
  for (int d = 1; d < 256; d <<= 1){
    int tv = (t >= d) ? sh[t - d] : 0;
    __syncthreads();
    sh[t] += tv;
    __syncthreads();
  }
  int excl = sh[t] - s;
  if (base + 0 < NN) off[base + 0] = excl;
  if (base + 1 < NN) off[base + 1] = excl + v.x;
  if (base + 2 < NN) off[base + 2] = excl + v.x + v.y;
  if (base + 3 < NN) off[base + 3] = excl + v.x + v.y + v.z;
  if (t == 255) parts[arr * 128 + b] = sh[255];
}

__global__ void scan2_kernel(int* __restrict__ parts){
  int t = threadIdx.x;
  if (t < 2){
    int run = 0;
    for (int b = 0; b < 98; ++b){ int v = parts[t * 128 + b]; parts[t * 128 + b] = run; run += v; }
  }
}

__global__ void scan3_kernel(const int* __restrict__ parts,
                             const int* __restrict__ cnt_p, const int* __restrict__ cnt_n,
                             int* __restrict__ off_p, int* __restrict__ off_n,
                             int* __restrict__ cur_p, int* __restrict__ cur_n,
                             float* __restrict__ rp, float* __restrict__ rn){
  const int arr = blockIdx.y;
  int i = blockIdx.x * 256 + threadIdx.x;
  if (i < NN){
    if (arr == 0){
      int o = off_p[i] + parts[i >> 10];
      off_p[i] = o; cur_p[i] = o;
      rp[i] = 1.0f / fmaxf((float)cnt_p[i], 1.0f);
    } else {
      int o = off_n[i] + parts[128 + (i >> 10)];
      off_n[i] = o; cur_n[i] = o;
      rn[i] = 1.0f / fmaxf((float)cnt_n[i], 1.0f);
    }
  }
  if (blockIdx.x == 0 && threadIdx.x == 0){
    if (arr == 0) off_p[NN] = EE; else off_n[NN] = EE;
  }
}

__global__ void scatter_kernel(const int* __restrict__ pe, const int* __restrict__ ne,
                               int* __restrict__ cur_p, int* __restrict__ cur_n,
                               int* __restrict__ srcp, int* __restrict__ srcn){
  int t = blockIdx.x * 256 + threadIdx.x;
  if (t < EE){
    int p = atomicAdd(&cur_p[pe[EE + t]], 1);
    srcp[p] = pe[t];
  } else if (t < 2 * EE){
    int u = t - EE;
    int p = atomicAdd(&cur_n[ne[EE + u]], 1);
    srcn[p] = ne[u];
  }
}

// ---------------- aggregation (gather) ----------------
// One wave per (node, edge-type); lane holds 2 features. Mean included (rcp).
__global__ __launch_bounds__(256) void agg_gather_kernel(const float* __restrict__ feat,
    const int* __restrict__ srcp, const int* __restrict__ srcn,
    const int* __restrict__ off_p, const int* __restrict__ off_n,
    const float* __restrict__ rp, const float* __restrict__ rn,
    float* __restrict__ sp, float* __restrict__ sn){
  int wid  = (blockIdx.x * 256 + threadIdx.x) >> 6;
  int lane = threadIdx.x & 63;
  if (wid >= 2 * NN) return;
  int nidx; const int* srcl; const int* off; const float* rcp; float* outp;
  if (wid < NN){ nidx = wid;      srcl = srcp; off = off_p; rcp = rp; outp = sp; }
  else         { nidx = wid - NN; srcl = srcn; off = off_n; rcp = rn; outp = sn; }
  int j = off[nidx], e = off[nidx + 1];
  float ax = 0.f, ay = 0.f, bx = 0.f, by = 0.f;
  for (; j + 1 < e; j += 2){
    int s0 = srcl[j], s1 = srcl[j + 1];
    float2 v0 = *(const float2*)(feat + (size_t)s0 * HH + lane * 2);
    float2 v1 = *(const float2*)(feat + (size_t)s1 * HH + lane * 2);
    ax += v0.x; ay += v0.y; bx += v1.x; by += v1.y;
  }
  if (j < e){
    int s0 = srcl[j];
    float2 v0 = *(const float2*)(feat + (size_t)s0 * HH + lane * 2);
    ax += v0.x; ay += v0.y;
  }
  float r = rcp[nidx];
  float2 o; o.x = (ax + bx) * r; o.y = (ay + by) * r;
  *(float2*)(outp + (size_t)nidx * HH + lane * 2) = o;
}

// ---------------- weight prep ----------------

__global__ void prep_kernel(const float* __restrict__ c0_pl, const float* __restrict__ c0_pr,
                            const float* __restrict__ c0_nl, const float* __restrict__ c0_nr,
                            const float* __restrict__ c1_pl, const float* __restrict__ c1_pr,
                            const float* __restrict__ c1_nl, const float* __restrict__ c1_nr,
                            const float* __restrict__ pw1, const float* __restrict__ pw2,
                            float* __restrict__ WT){
  int t = blockIdx.x * 256 + threadIdx.x;
  if (t >= 90112) return;
  if (t < 8192){                       // WT0pl [128][64] = c0_pl^T
    int k = t >> 6, j = t & 63; WT[t] = c0_pl[j * 128 + k];
  } else if (t < 16384){               // WT0nl
    int u = t - 8192; int k = u >> 6, j = u & 63; WT[t] = c0_nl[j * 128 + k];
  } else if (t < 32768){               // WT0r [128][128] = [c0_pr^T | c0_nr^T]
    int u = t - 16384; int k = u >> 7, j = u & 127;
    WT[t] = (j < 64) ? c0_pr[j * 128 + k] : c0_nr[(j - 64) * 128 + k];
  } else if (t < 36864){               // P1 = c1_pl[:, :64]^T
    int u = t - 32768; int k = u >> 6, j = u & 63; WT[t] = c1_pl[j * 128 + k];
  } else if (t < 40960){               // P2 = c1_nl[:, :64]^T
    int u = t - 36864; int k = u >> 6, j = u & 63; WT[t] = c1_nl[j * 128 + k];
  } else if (t < 45056){               // P3 = c1_nl[:, 64:]^T
    int u = t - 40960; int k = u >> 6, j = u & 63; WT[t] = c1_nl[j * 128 + 64 + k];
  } else if (t < 49152){               // P4 = c1_pl[:, 64:]^T
    int u = t - 45056; int k = u >> 6, j = u & 63; WT[t] = c1_pl[j * 128 + 64 + k];
  } else if (t < 53248){               // P5 = c1_pr^T (64x64)
    int u = t - 49152; int k = u >> 6, j = u & 63; WT[t] = c1_pr[j * 64 + k];
  } else if (t < 57344){               // P6 = c1_nr^T (64x64)
    int u = t - 53248; int k = u >> 6, j = u & 63; WT[t] = c1_nr[j * 64 + k];
  } else if (t < 73728){               // WTp1 = pw1^T [128][128]
    int u = t - 57344; int k = u >> 7, j = u & 127; WT[t] = pw1[j * 128 + k];
  } else {                             // WTp2 = pw2^T
    int u = t - 73728; int k = u >> 7, j = u & 127; WT[t] = pw2[j * 128 + k];
  }
}

// ---------------- fused conv+relu+LN layers ----------------

__global__ __launch_bounds__(256) void l0_kernel(
    const float* __restrict__ x, const float* __restrict__ sp, const float* __restrict__ sn,
    const float* __restrict__ WT,
    const float* __restrict__ biasP, const float* __restrict__ biasN,
    const float* __restrict__ lng, const float* __restrict__ lnb,
    float* __restrict__ h0)
{
  __shared__ float smem[4352 + 8192];
  float* As = smem; float* Bs = smem + 4352;
  const int node_base = blockIdx.x << 6;
  const int jq = (threadIdx.x & 15) << 2;
  const int mb = (threadIdx.x >> 4) << 2;
  float accP[4][4] = {}; float accN[4][4] = {};

  // phase 1: ap @ c0_pl^T  (POS)
  #pragma unroll
  for (int kk = 0; kk < 128; kk += 64){
    __syncthreads();
    stage_A(As, sp, node_base, kk);
    stage_B(Bs, WT + 0 + kk * 64, 1024);
    __syncthreads();
    gemm64(As, Bs, accP, mb, jq);
  }
  // phase 2: an @ c0_nl^T  (NEG)
  #pragma unroll
  for (int kk = 0; kk < 128; kk += 64){
    __syncthreads();
    stage_A(As, sn, node_base, kk);
    stage_B(Bs, WT + 8192 + kk * 64, 1024);
    __syncthreads();
    gemm64(As, Bs, accN, mb, jq);
  }
  // phase 3: x @ [c0_pr^T | c0_nr^T]  (BOTH)
  #pragma unroll
  for (int kk = 0; kk < 128; kk += 64){
    __syncthreads();
    stage_A(As, x, node_base, kk);
    stage_B(Bs, WT + 16384 + kk * 128, 2048);
    __syncthreads();
    gemm128(As, Bs, accP, accN, mb, jq);
  }
  ln_epilogue(accP, accN, biasP, biasN, lng, lnb, h0, node_base, mb, jq);
}

__global__ __launch_bounds__(256) void l1_kernel(
    const float* __restrict__ h0, const float* __restrict__ sp, const float* __restrict__ sn,
    const float* __restrict__ WT,
    const float* __restrict__ biasP, const float* __restrict__ biasN,
    const float* __restrict__ lng, const float* __restrict__ lnb,
    float* __restrict__ h1)
{
  __shared__ float smem[4352 + 8192];
  float* As = smem; float* Bs = smem + 4352;
  const int node_base = blockIdx.x << 6;
  const int jq = (threadIdx.x & 15) << 2;
  const int mb = (threadIdx.x >> 4) << 2;
  float accP[4][4] = {}; float accN[4][4] = {};

  // sp = A_pos(h0) = [aggP(xp)|aggP(xn)], sn = A_neg(h0) = [aggN(xp)|aggN(xn)]
  // ph1: aggP(xp) @ c1_pl[:, :64]^T -> POS
  __syncthreads(); stage_A(As, sp, node_base, 0);  stage_B(Bs, WT + 32768, 1024);
  __syncthreads(); gemm64(As, Bs, accP, mb, jq);
  // ph2: aggP(xn) @ c1_nl[:, :64]^T -> NEG
  __syncthreads(); stage_A(As, sp, node_base, 64); stage_B(Bs, WT + 36864, 1024);
  __syncthreads(); gemm64(As, Bs, accN, mb, jq);
  // ph3: aggN(xp) @ c1_nl[:, 64:]^T -> NEG
  __syncthreads(); stage_A(As, sn, node_base, 0);  stage_B(Bs, WT + 40960, 1024);
  __syncthreads(); gemm64(As, Bs, accN, mb, jq);
  // ph4: aggN(xn) @ c1_pl[:, 64:]^T -> POS
  __syncthreads(); stage_A(As, sn, node_base, 64); stage_B(Bs, WT + 45056, 1024);
  __syncthreads(); gemm64(As, Bs, accP, mb, jq);
  // ph5: xp @ c1_pr^T -> POS
  __syncthreads(); stage_A(As, h0, node_base, 0);  stage_B(Bs, WT + 49152, 1024);
  __syncthreads(); gemm64(As, Bs, accP, mb, jq);
  // ph6: xn @ c1_nr^T -> NEG
  __syncthreads(); stage_A(As, h0, node_base, 64); stage_B(Bs, WT + 53248, 1024);
  __syncthreads(); gemm64(As, Bs, accN, mb, jq);

  // NOTE: h1 may alias sp — safe: block reads only its own 64 sp-rows (ph1-2),
  // all such reads complete before ph3's barrier; epilogue writes same own rows.
  ln_epilogue(accP, accN, biasP, biasN, lng, lnb, h1, node_base, mb, jq);
}

__global__ __launch_bounds__(256) void mlp_kernel(
    const float* __restrict__ h1, const float* __restrict__ x0,
    const float* __restrict__ WT, const float* __restrict__ pb1, const float* __restrict__ pb2,
    const float* __restrict__ gate, float* __restrict__ out)
{
  __shared__ float smem[8448 + 8192];
  float* As = smem;            // [64][68] during GEMM1
  float* T  = smem;            // [64][132] afterwards (overlaps As; dead by then)
  float* Bs = smem + 8448;
  const int node_base = blockIdx.x << 6;
  const int jq = (threadIdx.x & 15) << 2;
  const int mb = (threadIdx.x >> 4) << 2;
  float accP[4][4] = {}; float accN[4][4] = {};

  #pragma unroll
  for (int kk = 0; kk < 128; kk += 64){
    __syncthreads();
    stage_A(As, h1, node_base, kk);
    stage_B(Bs, WT + 57344 + kk * 128, 2048);
    __syncthreads();
    gemm128(As, Bs, accP, accN, mb, jq);
  }
  __syncthreads();  // everyone done reading As before T overwrites it
  {
    float4 p1p = *(const float4*)(pb1 + jq);
    float4 p1n = *(const float4*)(pb1 + 64 + jq);
    #pragma unroll
    for (int i = 0; i < 4; ++i){
      float4 tp, tn;
      tp.x = gelu_f(accP[i][0] + p1p.x);
      tp.y = gelu_f(accP[i][1] + p1p.y);
      tp.z = gelu_f(accP[i][2] + p1p.z);
      tp.w = gelu_f(accP[i][3] + p1p.w);
      tn.x = gelu_f(accN[i][0] + p1n.x);
      tn.y = gelu_f(accN[i][1] + p1n.y);
      tn.z = gelu_f(accN[i][2] + p1n.z);
      tn.w = gelu_f(accN[i][3] + p1n.w);
      *(float4*)(T + (mb + i) * 132 + jq) = tp;
      *(float4*)(T + (mb + i) * 132 + 64 + jq) = tn;
    }
  }
  #pragma unroll
  for (int i = 0; i < 4; ++i)
    #pragma unroll
    for (int q = 0; q < 4; ++q){ accP[i][q] = 0.f; accN[i][q] = 0.f; }

  #pragma unroll
  for (int kk = 0; kk < 128; kk += 64){
    __syncthreads();               // first iter: T writes visible to all
    stage_B(Bs, WT + 73728 + kk * 128, 2048);
    __syncthreads();
    gemmT(T, Bs, accP, accN, mb, jq, kk);
  }

  float gt = gate[0], og = 1.0f - gt;
  float4 p2p = *(const float4*)(pb2 + jq);
  float4 p2n = *(const float4*)(pb2 + 64 + jq);
  #pragma unroll
  for (int i = 0; i < 4; ++i){
    int node = node_base + mb + i;
    if (node < NN){
      float4 xr = *(const float4*)(x0 + (size_t)node * HH + jq);
      float4 o;
      o.x = gt * (accP[i][0] + p2p.x) + og * xr.x;
      o.y = gt * (accP[i][1] + p2p.y) + og * xr.y;
      o.z = gt * (accP[i][2] + p2p.z) + og * xr.z;
      o.w = gt * (accP[i][3] + p2p.w) + og * xr.w;
      *(float4*)(out + (size_t)node * HH + jq) = o;
      xr = *(const float4*)(x0 + (size_t)node * HH + 64 + jq);
      o.x = gt * (accN[i][0] + p2n.x) + og * xr.x;
      o.y = gt * (accN[i][1] + p2n.y) + og * xr.y;
      o.z = gt * (accN[i][2] + p2n.z) + og * xr.z;
      o.w = gt * (accN[i][3] + p2n.w) + og * xr.w;
      *(float4*)(out + (size_t)node * HH + 64 + jq) = o;
    }
  }
}

// ---------------- launch ----------------

extern "C" void kernel_launch(void* const* d_in, const int* in_sizes, int n_in,
                              void* d_out, int out_size, void* d_ws, size_t ws_size,
                              hipStream_t stream){
  (void)in_sizes; (void)n_in; (void)out_size;
  const float* x     = (const float*)d_in[0];
  const int*   pe    = (const int*)d_in[1];
  const int*   ne    = (const int*)d_in[2];
  const float* c0_pl = (const float*)d_in[3];
  const float* c0_pr = (const float*)d_in[4];
  const float* c0_pr_b = (const float*)d_in[5];
  const float* c0_nl = (const float*)d_in[6];
  const float* c0_nr = (const float*)d_in[7];
  const float* c0_nr_b = (const float*)d_in[8];
  const float* c1_pl = (const float*)d_in[9];
  const float* c1_pr = (const float*)d_in[10];
  const float* c1_pr_b = (const float*)d_in[11];
  const float* c1_nl = (const float*)d_in[12];
  const float* c1_nr = (const float*)d_in[13];
  const float* c1_nr_b = (const float*)d_in[14];
  const float* ln0_g = (const float*)d_in[15];
  const float* ln0_b = (const float*)d_in[16];
  const float* ln1_g = (const float*)d_in[17];
  const float* ln1_b = (const float*)d_in[18];
  const float* pw1   = (const float*)d_in[19];
  const float* pb1   = (const float*)d_in[20];
  const float* pw2   = (const float*)d_in[21];
  const float* pb2   = (const float*)d_in[22];
  const float* gate  = (const float*)d_in[23];
  float* out = (float*)d_out;
  float* ws  = (float*)d_ws;

  // Workspace layout. h0 lives in d_out (dead before mlp writes final output);
  // h1 aliases s_pos (row-local, see l1_kernel note). ~112 MB total.
  float* s_pos = ws;                                   // N*128 (then h1)
  float* s_neg = ws + (size_t)NN * HH;                 // N*128
  float* rp    = ws + (size_t)2 * NN * HH;             // N
  float* rn    = rp + NN;                              // N
  float* WT    = rn + NN;                              // 90112
  int* cnt_p = (int*)(WT + 90112);                     // N
  int* cnt_n = cnt_p + NN;                             // N
  int* off_p = cnt_n + NN;                             // N+1
  int* off_n = off_p + NN + 1;                         // N+1
  int* cur_p = off_n + NN + 1;                         // N
  int* cur_n = cur_p + NN;                             // N
  int* parts = cur_n + NN;                             // 256
  int* srcp  = parts + 256;                            // E
  int* srcn  = srcp + EE;                              // E
  const size_t need = (size_t)((char*)(srcn + EE) - (char*)ws);
  if (ws_size < need) return;  // defensive: never scribble OOB

  hipMemsetAsync(cnt_p, 0, (size_t)2 * NN * sizeof(int), stream);
  prep_kernel<<<352, 256, 0, stream>>>(c0_pl, c0_pr, c0_nl, c0_nr,
                                       c1_pl, c1_pr, c1_nl, c1_nr, pw1, pw2, WT);
  hist_kernel<<<(2 * EE) / 256, 256, 0, stream>>>(pe, ne, cnt_p, cnt_n);
  scan1_kernel<<<dim3(98, 2), 256, 0, stream>>>(cnt_p, cnt_n, off_p, off_n, parts);
  scan2_kernel<<<1, 64, 0, stream>>>(parts);
  scan3_kernel<<<dim3(391, 2), 256, 0, stream>>>(parts, cnt_p, cnt_n, off_p, off_n,
                                                 cur_p, cur_n, rp, rn);
  scatter_kernel<<<(2 * EE) / 256, 256, 0, stream>>>(pe, ne, cur_p, cur_n, srcp, srcn);

  // layer 0
  agg_gather_kernel<<<(2 * NN * 64) / 256, 256, 0, stream>>>(x, srcp, srcn, off_p, off_n,
                                                             rp, rn, s_pos, s_neg);
  l0_kernel<<<(NN + 63) / 64, 256, 0, stream>>>(x, s_pos, s_neg, WT,
                                                c0_pr_b, c0_nr_b, ln0_g, ln0_b, out /*h0*/);
  // layer 1 (reuse CSR; aggregate full-width h0 once per sign)
  agg_gather_kernel<<<(2 * NN * 64) / 256, 256, 0, stream>>>(out /*h0*/, srcp, srcn, off_p, off_n,
                                                             rp, rn, s_pos, s_neg);
  l1_kernel<<<(NN + 63) / 64, 256, 0, stream>>>(out /*h0*/, s_pos, s_neg, WT,
                                                c1_pr_b, c1_nr_b, ln1_g, ln1_b, s_pos /*h1*/);
  // MLP + gated residual
  mlp_kernel<<<(NN + 63) / 64, 256, 0, stream>>>(s_pos /*h1*/, x, WT, pb1, pb2, gate, out);
}

// Round 8
// 881.594 us; speedup vs baseline: 3.5717x; 1.0888x over previous
//
#include <hip/hip_runtime.h>
#include <cstddef>

#define NN 100000
#define HH 128
#define H2C 64
#define EE 800000

// ---------------- helpers ----------------

__device__ __forceinline__ float gelu_f(float v){
  return 0.5f * v * (1.0f + erff(v * 0.70710678118654752f));
}

__device__ __forceinline__ float red16(float s){
  s += __shfl_xor(s, 1);
  s += __shfl_xor(s, 2);
  s += __shfl_xor(s, 4);
  s += __shfl_xor(s, 8);
  return s;
}

// Stage a 64-node x 64-k chunk of A into As[64][68] (pad 4 -> conflict-free reads).
__device__ __forceinline__ void stage_A(float* As, const float* __restrict__ src,
                                        int node_base, int col_off){
  const int t = threadIdx.x;
  #pragma unroll
  for (int i = 0; i < 4; ++i){
    int idx4 = t + i * 256;          // 1024 float4 total
    int m  = idx4 >> 4;              // node within tile
    int k4 = idx4 & 15;              // float4 within 64-k slice
    int node = node_base + m;
    float4 v = make_float4(0.f, 0.f, 0.f, 0.f);
    if (node < NN){
      v = *(const float4*)(src + (size_t)node * HH + col_off + (k4 << 2));
    }
    *(float4*)(As + m * 68 + (k4 << 2)) = v;
  }
}

// Copy a packed k-major weight chunk into Bs.
__device__ __forceinline__ void stage_B(float* Bs, const float* __restrict__ src, int nfloat4){
  for (int idx4 = threadIdx.x; idx4 < nfloat4; idx4 += 256){
    *(float4*)(Bs + (idx4 << 2)) = *(const float4*)(src + (idx4 << 2));
  }
}

// 64-wide B (single output quad), accumulate into acc[4][4]
__device__ __forceinline__ void gemm64(const float* As, const float* Bs,
                                       float (*acc)[4], int mb, int jq){
  #pragma unroll 8
  for (int k = 0; k < 64; ++k){
    float4 bq = *(const float4*)(Bs + (k << 6) + jq);
    float a0 = As[(mb + 0) * 68 + k];
    float a1 = As[(mb + 1) * 68 + k];
    float a2 = As[(mb + 2) * 68 + k];
    float a3 = As[(mb + 3) * 68 + k];
    acc[0][0] += a0 * bq.x; acc[0][1] += a0 * bq.y; acc[0][2] += a0 * bq.z; acc[0][3] += a0 * bq.w;
    acc[1][0] += a1 * bq.x; acc[1][1] += a1 * bq.y; acc[1][2] += a1 * bq.z; acc[1][3] += a1 * bq.w;
    acc[2][0] += a2 * bq.x; acc[2][1] += a2 * bq.y; acc[2][2] += a2 * bq.z; acc[2][3] += a2 * bq.w;
    acc[3][0] += a3 * bq.x; acc[3][1] += a3 * bq.y; acc[3][2] += a3 * bq.z; acc[3][3] += a3 * bq.w;
  }
}

// 128-wide B (both quads), accumulate into accP/accN
__device__ __forceinline__ void gemm128(const float* As, const float* Bs,
                                        float (*accP)[4], float (*accN)[4], int mb, int jq){
  #pragma unroll 4
  for (int k = 0; k < 64; ++k){
    float4 bp = *(const float4*)(Bs + (k << 7) + jq);
    float4 bn = *(const float4*)(Bs + (k << 7) + 64 + jq);
    float a0 = As[(mb + 0) * 68 + k];
    float a1 = As[(mb + 1) * 68 + k];
    float a2 = As[(mb + 2) * 68 + k];
    float a3 = As[(mb + 3) * 68 + k];
    accP[0][0] += a0 * bp.x; accP[0][1] += a0 * bp.y; accP[0][2] += a0 * bp.z; accP[0][3] += a0 * bp.w;
    accP[1][0] += a1 * bp.x; accP[1][1] += a1 * bp.y; accP[1][2] += a1 * bp.z; accP[1][3] += a1 * bp.w;
    accP[2][0] += a2 * bp.x; accP[2][1] += a2 * bp.y; accP[2][2] += a2 * bp.z; accP[2][3] += a2 * bp.w;
    accP[3][0] += a3 * bp.x; accP[3][1] += a3 * bp.y; accP[3][2] += a3 * bp.z; accP[3][3] += a3 * bp.w;
    accN[0][0] += a0 * bn.x; accN[0][1] += a0 * bn.y; accN[0][2] += a0 * bn.z; accN[0][3] += a0 * bn.w;
    accN[1][0] += a1 * bn.x; accN[1][1] += a1 * bn.y; accN[1][2] += a1 * bn.z; accN[1][3] += a1 * bn.w;
    accN[2][0] += a2 * bn.x; accN[2][1] += a2 * bn.y; accN[2][2] += a2 * bn.z; accN[2][3] += a2 * bn.w;
    accN[3][0] += a3 * bn.x; accN[3][1] += a3 * bn.y; accN[3][2] += a3 * bn.z; accN[3][3] += a3 * bn.w;
  }
}

// GEMM with A = T in LDS laid out [64][132], k offset kk
__device__ __forceinline__ void gemmT(const float* T, const float* Bs,
                                      float (*accP)[4], float (*accN)[4], int mb, int jq, int kk){
  #pragma unroll 4
  for (int k = 0; k < 64; ++k){
    float4 bp = *(const float4*)(Bs + (k << 7) + jq);
    float4 bn = *(const float4*)(Bs + (k << 7) + 64 + jq);
    float a0 = T[(mb + 0) * 132 + kk + k];
    float a1 = T[(mb + 1) * 132 + kk + k];
    float a2 = T[(mb + 2) * 132 + kk + k];
    float a3 = T[(mb + 3) * 132 + kk + k];
    accP[0][0] += a0 * bp.x; accP[0][1] += a0 * bp.y; accP[0][2] += a0 * bp.z; accP[0][3] += a0 * bp.w;
    accP[1][0] += a1 * bp.x; accP[1][1] += a1 * bp.y; accP[1][2] += a1 * bp.z; accP[1][3] += a1 * bp.w;
    accP[2][0] += a2 * bp.x; accP[2][1] += a2 * bp.y; accP[2][2] += a2 * bp.z; accP[2][3] += a2 * bp.w;
    accP[3][0] += a3 * bp.x; accP[3][1] += a3 * bp.y; accP[3][2] += a3 * bp.z; accP[3][3] += a3 * bp.w;
    accN[0][0] += a0 * bn.x; accN[0][1] += a0 * bn.y; accN[0][2] += a0 * bn.z; accN[0][3] += a0 * bn.w;
    accN[1][0] += a1 * bn.x; accN[1][1] += a1 * bn.y; accN[1][2] += a1 * bn.z; accN[1][3] += a1 * bn.w;
    accN[2][0] += a2 * bn.x; accN[2][1] += a2 * bn.y; accN[2][2] += a2 * bn.z; accN[2][3] += a2 * bn.w;
    accN[3][0] += a3 * bn.x; accN[3][1] += a3 * bn.y; accN[3][2] += a3 * bn.z; accN[3][3] += a3 * bn.w;
  }
}

// relu + LayerNorm epilogue; values for one node row live in 16 consecutive lanes.
__device__ __forceinline__ void ln_epilogue(float (*accP)[4], float (*accN)[4],
    const float* __restrict__ biasP, const float* __restrict__ biasN,
    const float* __restrict__ g, const float* __restrict__ b,
    float* __restrict__ out, int node_base, int mb, int jq)
{
  float4 bp  = *(const float4*)(biasP + jq);
  float4 bn  = *(const float4*)(biasN + jq);
  float4 gp  = *(const float4*)(g + jq);
  float4 gn  = *(const float4*)(g + 64 + jq);
  float4 b0p = *(const float4*)(b + jq);
  float4 b0n = *(const float4*)(b + 64 + jq);
  #pragma unroll
  for (int i = 0; i < 4; ++i){
    int node = node_base + mb + i;
    float v0 = fmaxf(accP[i][0] + bp.x, 0.f);
    float v1 = fmaxf(accP[i][1] + bp.y, 0.f);
    float v2 = fmaxf(accP[i][2] + bp.z, 0.f);
    float v3 = fmaxf(accP[i][3] + bp.w, 0.f);
    float v4 = fmaxf(accN[i][0] + bn.x, 0.f);
    float v5 = fmaxf(accN[i][1] + bn.y, 0.f);
    float v6 = fmaxf(accN[i][2] + bn.z, 0.f);
    float v7 = fmaxf(accN[i][3] + bn.w, 0.f);
    float s = v0 + v1 + v2 + v3 + v4 + v5 + v6 + v7;
    s = red16(s);
    float mu = s * (1.0f / 128.0f);
    float d0 = v0 - mu, d1 = v1 - mu, d2 = v2 - mu, d3 = v3 - mu;
    float d4 = v4 - mu, d5 = v5 - mu, d6 = v6 - mu, d7 = v7 - mu;
    float q = d0*d0 + d1*d1 + d2*d2 + d3*d3 + d4*d4 + d5*d5 + d6*d6 + d7*d7;
    q = red16(q);
    float rstd = rsqrtf(q * (1.0f / 128.0f) + 1e-5f);
    if (node < NN){
      float4 o;
      o.x = d0 * rstd * gp.x + b0p.x;
      o.y = d1 * rstd * gp.y + b0p.y;
      o.z = d2 * rstd * gp.z + b0p.z;
      o.w = d3 * rstd * gp.w + b0p.w;
      *(float4*)(out + (size_t)node * HH + jq) = o;
      o.x = d4 * rstd * gn.x + b0n.x;
      o.y = d5 * rstd * gn.y + b0n.y;
      o.z = d6 * rstd * gn.z + b0n.z;
      o.w = d7 * rstd * gn.w + b0n.w;
      *(float4*)(out + (size_t)node * HH + 64 + jq) = o;
    }
  }
}

// ---------------- CSR build ----------------

__global__ void hist_kernel(const int* __restrict__ pe, const int* __restrict__ ne,
                            int* __restrict__ cnt_p, int* __restrict__ cnt_n){
  int t = blockIdx.x * 256 + threadIdx.x;
  if (t < EE)            atomicAdd(&cnt_p[pe[EE + t]], 1);
  else if (t < 2 * EE)   atomicAdd(&cnt_n[ne[EE + (t - EE)]], 1);
}

// scan1: 98 blocks x 256 thr x (4 elem) per array; local exclusive prefix into off,
// block totals into parts[arr*128 + b].
__global__ void scan1_kernel(const int* __restrict__ cnt_p, const int* __restrict__ cnt_n,
                             int* __restrict__ off_p, int* __restrict__ off_n,
                             int* __restrict__ parts){
  __shared__ int sh[256];
  const int arr = blockIdx.y;
  const int* cnt = arr ? cnt_n : cnt_p;
  int* off = arr ? off_n : off_p;
  const int b = blockIdx.x, t = threadIdx.x;
  const int base = b * 1024 + t * 4;
  int4 v = make_int4(0, 0, 0, 0);
  if (base + 3 < NN) v = *(const int4*)(cnt + base);
  else {
    if (base + 0 < NN) v.x = cnt[base + 0];
    if (base + 1 < NN) v.y = cnt[base + 1];
    if (base + 2 < NN) v.z = cnt[base + 2];
  }
  int s = v.x + v.y + v.z + v.w;
  sh[t] = s; __syncthreads();
  for (int d = 1; d < 256; d <<= 1){
    int tv = (t >= d) ? sh[t - d] : 0;
    __syncthreads();
    sh[t] += tv;
    __syncthreads();
  }
  int excl = sh[t] - s;
  if (base + 0 < NN) off[base + 0] = excl;
  if (base + 1 < NN) off[base + 1] = excl + v.x;
  if (base + 2 < NN) off[base + 2] = excl + v.x + v.y;
  if (base + 3 < NN) off[base + 3] = excl + v.x + v.y + v.z;
  if (t == 255) parts[arr * 128 + b] = sh[255];
}

__global__ void scan2_kernel(int* __restrict__ parts){
  int t = threadIdx.x;
  if (t < 2){
    int run = 0;
    for (int b = 0; b < 98; ++b){ int v = parts[t * 128 + b]; parts[t * 128 + b] = run; run += v; }
  }
}

__global__ void scan3_kernel(const int* __restrict__ parts,
                             const int* __restrict__ cnt_p, const int* __restrict__ cnt_n,
                             int* __restrict__ off_p, int* __restrict__ off_n,
                             int* __restrict__ cur_p, int* __restrict__ cur_n,
                             float* __restrict__ rp, float* __restrict__ rn){
  const int arr = blockIdx.y;
  int i = blockIdx.x * 256 + threadIdx.x;
  if (i < NN){
    if (arr == 0){
      int o = off_p[i] + parts[i >> 10];
      off_p[i] = o; cur_p[i] = o;
      rp[i] = 1.0f / fmaxf((float)cnt_p[i], 1.0f);
    } else {
      int o = off_n[i] + parts[128 + (i >> 10)];
      off_n[i] = o; cur_n[i] = o;
      rn[i] = 1.0f / fmaxf((float)cnt_n[i], 1.0f);
    }
  }
  if (blockIdx.x == 0 && threadIdx.x == 0){
    if (arr == 0) off_p[NN] = EE; else off_n[NN] = EE;
  }
}

__global__ void scatter_kernel(const int* __restrict__ pe, const int* __restrict__ ne,
                               int* __restrict__ cur_p, int* __restrict__ cur_n,
                               int* __restrict__ srcp, int* __restrict__ srcn){
  int t = blockIdx.x * 256 + threadIdx.x;
  if (t < EE){
    int p = atomicAdd(&cur_p[pe[EE + t]], 1);
    srcp[p] = pe[t];
  } else if (t < 2 * EE){
    int u = t - EE;
    int p = atomicAdd(&cur_n[ne[EE + u]], 1);
    srcn[p] = ne[u];
  }
}

// ---------------- aggregation (gather) ----------------
// One wave per (node, edge-type); lane holds 2 features. Mean included (rcp).
// 4 edges in flight per iteration (latency-bound fix, r6: VALUBusy 19%, hbm 36%).
__global__ __launch_bounds__(256) void agg_gather_kernel(const float* __restrict__ feat,
    const int* __restrict__ srcp, const int* __restrict__ srcn,
    const int* __restrict__ off_p, const int* __restrict__ off_n,
    const float* __restrict__ rp, const float* __restrict__ rn,
    float* __restrict__ sp, float* __restrict__ sn){
  int wid  = (blockIdx.x * 256 + threadIdx.x) >> 6;
  int lane = threadIdx.x & 63;
  if (wid >= 2 * NN) return;
  int nidx; const int* srcl; const int* off; const float* rcp; float* outp;
  if (wid < NN){ nidx = wid;      srcl = srcp; off = off_p; rcp = rp; outp = sp; }
  else         { nidx = wid - NN; srcl = srcn; off = off_n; rcp = rn; outp = sn; }
  int j = off[nidx], e = off[nidx + 1];
  const int fo = lane * 2;
  float a0x = 0.f, a0y = 0.f, a1x = 0.f, a1y = 0.f;
  float a2x = 0.f, a2y = 0.f, a3x = 0.f, a3y = 0.f;
  for (; j + 3 < e; j += 4){
    int s0 = srcl[j], s1 = srcl[j + 1], s2 = srcl[j + 2], s3 = srcl[j + 3];
    float2 v0 = *(const float2*)(feat + (size_t)s0 * HH + fo);
    float2 v1 = *(const float2*)(feat + (size_t)s1 * HH + fo);
    float2 v2 = *(const float2*)(feat + (size_t)s2 * HH + fo);
    float2 v3 = *(const float2*)(feat + (size_t)s3 * HH + fo);
    a0x += v0.x; a0y += v0.y;
    a1x += v1.x; a1y += v1.y;
    a2x += v2.x; a2y += v2.y;
    a3x += v3.x; a3y += v3.y;
  }
  if (j + 1 < e){
    int s0 = srcl[j], s1 = srcl[j + 1];
    float2 v0 = *(const float2*)(feat + (size_t)s0 * HH + fo);
    float2 v1 = *(const float2*)(feat + (size_t)s1 * HH + fo);
    a0x += v0.x; a0y += v0.y;
    a1x += v1.x; a1y += v1.y;
    j += 2;
  }
  if (j < e){
    int s0 = srcl[j];
    float2 v0 = *(const float2*)(feat + (size_t)s0 * HH + fo);
    a0x += v0.x; a0y += v0.y;
  }
  float r = rcp[nidx];
  float2 o;
  o.x = ((a0x + a1x) + (a2x + a3x)) * r;
  o.y = ((a0y + a1y) + (a2y + a3y)) * r;
  *(float2*)(outp + (size_t)nidx * HH + fo) = o;
}

// ---------------- weight prep ----------------

__global__ void prep_kernel(const float* __restrict__ c0_pl, const float* __restrict__ c0_pr,
                            const float* __restrict__ c0_nl, const float* __restrict__ c0_nr,
                            const float* __restrict__ c1_pl, const float* __restrict__ c1_pr,
                            const float* __restrict__ c1_nl, const float* __restrict__ c1_nr,
                            const float* __restrict__ pw1, const float* __restrict__ pw2,
                            float* __restrict__ WT){
  int t = blockIdx.x * 256 + threadIdx.x;
  if (t >= 90112) return;
  if (t < 8192){                       // WT0pl [128][64] = c0_pl^T
    int k = t >> 6, j = t & 63; WT[t] = c0_pl[j * 128 + k];
  } else if (t < 16384){               // WT0nl
    int u = t - 8192; int k = u >> 6, j = u & 63; WT[t] = c0_nl[j * 128 + k];
  } else if (t < 32768){               // WT0r [128][128] = [c0_pr^T | c0_nr^T]
    int u = t - 16384; int k = u >> 7, j = u & 127;
    WT[t] = (j < 64) ? c0_pr[j * 128 + k] : c0_nr[(j - 64) * 128 + k];
  } else if (t < 36864){               // P1 = c1_pl[:, :64]^T
    int u = t - 32768; int k = u >> 6, j = u & 63; WT[t] = c1_pl[j * 128 + k];
  } else if (t < 40960){               // P2 = c1_nl[:, :64]^T
    int u = t - 36864; int k = u >> 6, j = u & 63; WT[t] = c1_nl[j * 128 + k];
  } else if (t < 45056){               // P3 = c1_nl[:, 64:]^T
    int u = t - 40960; int k = u >> 6, j = u & 63; WT[t] = c1_nl[j * 128 + 64 + k];
  } else if (t < 49152){               // P4 = c1_pl[:, 64:]^T
    int u = t - 45056; int k = u >> 6, j = u & 63; WT[t] = c1_pl[j * 128 + 64 + k];
  } else if (t < 53248){               // P5 = c1_pr^T (64x64)
    int u = t - 49152; int k = u >> 6, j = u & 63; WT[t] = c1_pr[j * 64 + k];
  } else if (t < 57344){               // P6 = c1_nr^T (64x64)
    int u = t - 53248; int k = u >> 6, j = u & 63; WT[t] = c1_nr[j * 64 + k];
  } else if (t < 73728){               // WTp1 = pw1^T [128][128]
    int u = t - 57344; int k = u >> 7, j = u & 127; WT[t] = pw1[j * 128 + k];
  } else {                             // WTp2 = pw2^T
    int u = t - 73728; int k = u >> 7, j = u & 127; WT[t] = pw2[j * 128 + k];
  }
}

// ---------------- fused conv+relu+LN layers ----------------

__global__ __launch_bounds__(256) void l0_kernel(
    const float* __restrict__ x, const float* __restrict__ sp, const float* __restrict__ sn,
    const float* __restrict__ WT,
    const float* __restrict__ biasP, const float* __restrict__ biasN,
    const float* __restrict__ lng, const float* __restrict__ lnb,
    float* __restrict__ h0)
{
  __shared__ float smem[4352 + 8192];
  float* As = smem; float* Bs = smem + 4352;
  const int node_base = blockIdx.x << 6;
  const int jq = (threadIdx.x & 15) << 2;
  const int mb = (threadIdx.x >> 4) << 2;
  float accP[4][4] = {}; float accN[4][4] = {};

  // phase 1: ap @ c0_pl^T  (POS)
  #pragma unroll
  for (int kk = 0; kk < 128; kk += 64){
    __syncthreads();
    stage_A(As, sp, node_base, kk);
    stage_B(Bs, WT + 0 + kk * 64, 1024);
    __syncthreads();
    gemm64(As, Bs, accP, mb, jq);
  }
  // phase 2: an @ c0_nl^T  (NEG)
  #pragma unroll
  for (int kk = 0; kk < 128; kk += 64){
    __syncthreads();
    stage_A(As, sn, node_base, kk);
    stage_B(Bs, WT + 8192 + kk * 64, 1024);
    __syncthreads();
    gemm64(As, Bs, accN, mb, jq);
  }
  // phase 3: x @ [c0_pr^T | c0_nr^T]  (BOTH)
  #pragma unroll
  for (int kk = 0; kk < 128; kk += 64){
    __syncthreads();
    stage_A(As, x, node_base, kk);
    stage_B(Bs, WT + 16384 + kk * 128, 2048);
    __syncthreads();
    gemm128(As, Bs, accP, accN, mb, jq);
  }
  ln_epilogue(accP, accN, biasP, biasN, lng, lnb, h0, node_base, mb, jq);
}

__global__ __launch_bounds__(256) void l1_kernel(
    const float* __restrict__ h0, const float* __restrict__ sp, const float* __restrict__ sn,
    const float* __restrict__ WT,
    const float* __restrict__ biasP, const float* __restrict__ biasN,
    const float* __restrict__ lng, const float* __restrict__ lnb,
    float* __restrict__ h1)
{
  __shared__ float smem[4352 + 8192];
  float* As = smem; float* Bs = smem + 4352;
  const int node_base = blockIdx.x << 6;
  const int jq = (threadIdx.x & 15) << 2;
  const int mb = (threadIdx.x >> 4) << 2;
  float accP[4][4] = {}; float accN[4][4] = {};

  // sp = A_pos(h0) = [aggP(xp)|aggP(xn)], sn = A_neg(h0) = [aggN(xp)|aggN(xn)]
  // ph1: aggP(xp) @ c1_pl[:, :64]^T -> POS
  __syncthreads(); stage_A(As, sp, node_base, 0);  stage_B(Bs, WT + 32768, 1024);
  __syncthreads(); gemm64(As, Bs, accP, mb, jq);
  // ph2: aggP(xn) @ c1_nl[:, :64]^T -> NEG
  __syncthreads(); stage_A(As, sp, node_base, 64); stage_B(Bs, WT + 36864, 1024);
  __syncthreads(); gemm64(As, Bs, accN, mb, jq);
  // ph3: aggN(xp) @ c1_nl[:, 64:]^T -> NEG
  __syncthreads(); stage_A(As, sn, node_base, 0);  stage_B(Bs, WT + 40960, 1024);
  __syncthreads(); gemm64(As, Bs, accN, mb, jq);
  // ph4: aggN(xn) @ c1_pl[:, 64:]^T -> POS
  __syncthreads(); stage_A(As, sn, node_base, 64); stage_B(Bs, WT + 45056, 1024);
  __syncthreads(); gemm64(As, Bs, accP, mb, jq);
  // ph5: xp @ c1_pr^T -> POS
  __syncthreads(); stage_A(As, h0, node_base, 0);  stage_B(Bs, WT + 49152, 1024);
  __syncthreads(); gemm64(As, Bs, accP, mb, jq);
  // ph6: xn @ c1_nr^T -> NEG
  __syncthreads(); stage_A(As, h0, node_base, 64); stage_B(Bs, WT + 53248, 1024);
  __syncthreads(); gemm64(As, Bs, accN, mb, jq);

  // NOTE: h1 may alias sp — safe: block reads only its own 64 sp-rows (ph1-2),
  // all such reads complete before ph3's barrier; epilogue writes same own rows.
  ln_epilogue(accP, accN, biasP, biasN, lng, lnb, h1, node_base, mb, jq);
}

__global__ __launch_bounds__(256) void mlp_kernel(
    const float* __restrict__ h1, const float* __restrict__ x0,
    const float* __restrict__ WT, const float* __restrict__ pb1, const float* __restrict__ pb2,
    const float* __restrict__ gate, float* __restrict__ out)
{
  __shared__ float smem[8448 + 8192];
  float* As = smem;            // [64][68] during GEMM1
  float* T  = smem;            // [64][132] afterwards (overlaps As; dead by then)
  float* Bs = smem + 8448;
  const int node_base = blockIdx.x << 6;
  const int jq = (threadIdx.x & 15) << 2;
  const int mb = (threadIdx.x >> 4) << 2;
  float accP[4][4] = {}; float accN[4][4] = {};

  #pragma unroll
  for (int kk = 0; kk < 128; kk += 64){
    __syncthreads();
    stage_A(As, h1, node_base, kk);
    stage_B(Bs, WT + 57344 + kk * 128, 2048);
    __syncthreads();
    gemm128(As, Bs, accP, accN, mb, jq);
  }
  __syncthreads();  // everyone done reading As before T overwrites it
  {
    float4 p1p = *(const float4*)(pb1 + jq);
    float4 p1n = *(const float4*)(pb1 + 64 + jq);
    #pragma unroll
    for (int i = 0; i < 4; ++i){
      float4 tp, tn;
      tp.x = gelu_f(accP[i][0] + p1p.x);
      tp.y = gelu_f(accP[i][1] + p1p.y);
      tp.z = gelu_f(accP[i][2] + p1p.z);
      tp.w = gelu_f(accP[i][3] + p1p.w);
      tn.x = gelu_f(accN[i][0] + p1n.x);
      tn.y = gelu_f(accN[i][1] + p1n.y);
      tn.z = gelu_f(accN[i][2] + p1n.z);
      tn.w = gelu_f(accN[i][3] + p1n.w);
      *(float4*)(T + (mb + i) * 132 + jq) = tp;
      *(float4*)(T + (mb + i) * 132 + 64 + jq) = tn;
    }
  }
  #pragma unroll
  for (int i = 0; i < 4; ++i)
    #pragma unroll
    for (int q = 0; q < 4; ++q){ accP[i][q] = 0.f; accN[i][q] = 0.f; }

  #pragma unroll
  for (int kk = 0; kk < 128; kk += 64){
    __syncthreads();               // first iter: T writes visible to all
    stage_B(Bs, WT + 73728 + kk * 128, 2048);
    __syncthreads();
    gemmT(T, Bs, accP, accN, mb, jq, kk);
  }

  float gt = gate[0], og = 1.0f - gt;
  float4 p2p = *(const float4*)(pb2 + jq);
  float4 p2n = *(const float4*)(pb2 + 64 + jq);
  #pragma unroll
  for (int i = 0; i < 4; ++i){
    int node = node_base + mb + i;
    if (node < NN){
      float4 xr = *(const float4*)(x0 + (size_t)node * HH + jq);
      float4 o;
      o.x = gt * (accP[i][0] + p2p.x) + og * xr.x;
      o.y = gt * (accP[i][1] + p2p.y) + og * xr.y;
      o.z = gt * (accP[i][2] + p2p.z) + og * xr.z;
      o.w = gt * (accP[i][3] + p2p.w) + og * xr.w;
      *(float4*)(out + (size_t)node * HH + jq) = o;
      xr = *(const float4*)(x0 + (size_t)node * HH + 64 + jq);
      o.x = gt * (accN[i][0] + p2n.x) + og * xr.x;
      o.y = gt * (accN[i][1] + p2n.y) + og * xr.y;
      o.z = gt * (accN[i][2] + p2n.z) + og * xr.z;
      o.w = gt * (accN[i][3] + p2n.w) + og * xr.w;
      *(float4*)(out + (size_t)node * HH + 64 + jq) = o;
    }
  }
}

// ---------------- launch ----------------

extern "C" void kernel_launch(void* const* d_in, const int* in_sizes, int n_in,
                              void* d_out, int out_size, void* d_ws, size_t ws_size,
                              hipStream_t stream){
  (void)in_sizes; (void)n_in; (void)out_size;
  const float* x     = (const float*)d_in[0];
  const int*   pe    = (const int*)d_in[1];
  const int*   ne    = (const int*)d_in[2];
  const float* c0_pl = (const float*)d_in[3];
  const float* c0_pr = (const float*)d_in[4];
  const float* c0_pr_b = (const float*)d_in[5];
  const float* c0_nl = (const float*)d_in[6];
  const float* c0_nr = (const float*)d_in[7];
  const float* c0_nr_b = (const float*)d_in[8];
  const float* c1_pl = (const float*)d_in[9];
  const float* c1_pr = (const float*)d_in[10];
  const float* c1_pr_b = (const float*)d_in[11];
  const float* c1_nl = (const float*)d_in[12];
  const float* c1_nr = (const float*)d_in[13];
  const float* c1_nr_b = (const float*)d_in[14];
  const float* ln0_g = (const float*)d_in[15];
  const float* ln0_b = (const float*)d_in[16];
  const float* ln1_g = (const float*)d_in[17];
  const float* ln1_b = (const float*)d_in[18];
  const float* pw1   = (const float*)d_in[19];
  const float* pb1   = (const float*)d_in[20];
  const float* pw2   = (const float*)d_in[21];
  const float* pb2   = (const float*)d_in[22];
  const float* gate  = (const float*)d_in[23];
  float* out = (float*)d_out;
  float* ws  = (float*)d_ws;

  // Workspace layout. h0 lives in d_out (dead before mlp writes final output);
  // h1 aliases s_pos (row-local, see l1_kernel note). ~112 MB total.
  float* s_pos = ws;                                   // N*128 (then h1)
  float* s_neg = ws + (size_t)NN * HH;                 // N*128
  float* rp    = ws + (size_t)2 * NN * HH;             // N
  float* rn    = rp + NN;                              // N
  float* WT    = rn + NN;                              // 90112
  int* cnt_p = (int*)(WT + 90112);                     // N
  int* cnt_n = cnt_p + NN;                             // N
  int* off_p = cnt_n + NN;                             // N+1
  int* off_n = off_p + NN + 1;                         // N+1
  int* cur_p = off_n + NN + 1;                         // N
  int* cur_n = cur_p + NN;                             // N
  int* parts = cur_n + NN;                             // 256
  int* srcp  = parts + 256;                            // E
  int* srcn  = srcp + EE;                              // E
  const size_t need = (size_t)((char*)(srcn + EE) - (char*)ws);
  if (ws_size < need) return;  // defensive: never scribble OOB

  hipMemsetAsync(cnt_p, 0, (size_t)2 * NN * sizeof(int), stream);
  prep_kernel<<<352, 256, 0, stream>>>(c0_pl, c0_pr, c0_nl, c0_nr,
                                       c1_pl, c1_pr, c1_nl, c1_nr, pw1, pw2, WT);
  hist_kernel<<<(2 * EE) / 256, 256, 0, stream>>>(pe, ne, cnt_p, cnt_n);
  scan1_kernel<<<dim3(98, 2), 256, 0, stream>>>(cnt_p, cnt_n, off_p, off_n, parts);
  scan2_kernel<<<1, 64, 0, stream>>>(parts);
  scan3_kernel<<<dim3(391, 2), 256, 0, stream>>>(parts, cnt_p, cnt_n, off_p, off_n,
                                                 cur_p, cur_n, rp, rn);
  scatter_kernel<<<(2 * EE) / 256, 256, 0, stream>>>(pe, ne, cur_p, cur_n, srcp, srcn);

  // layer 0
  agg_gather_kernel<<<(2 * NN * 64) / 256, 256, 0, stream>>>(x, srcp, srcn, off_p, off_n,
                                                             rp, rn, s_pos, s_neg);
  l0_kernel<<<(NN + 63) / 64, 256, 0, stream>>>(x, s_pos, s_neg, WT,
                                                c0_pr_b, c0_nr_b, ln0_g, ln0_b, out /*h0*/);
  // layer 1 (reuse CSR; aggregate full-width h0 once per sign)
  agg_gather_kernel<<<(2 * NN * 64) / 256, 256, 0, stream>>>(out /*h0*/, srcp, srcn, off_p, off_n,
                                                             rp, rn, s_pos, s_neg);
  l1_kernel<<<(NN + 63) / 64, 256, 0, stream>>>(out /*h0*/, s_pos, s_neg, WT,
                                                c1_pr_b, c1_nr_b, ln1_g, ln1_b, s_pos /*h1*/);
  // MLP + gated residual
  mlp_kernel<<<(NN + 63) / 64, 256, 0, stream>>>(s_pos /*h1*/, x, WT, pb1, pb2, gate, out);
}

// Round 9
// 712.183 us; speedup vs baseline: 4.4213x; 1.2379x over previous
//
#include <hip/hip_runtime.h>
#include <cstddef>

#define NN 100000
#define HH 128
#define EE 800000

typedef __attribute__((ext_vector_type(8))) short bf16x8;   // 8 bf16 = 4 VGPRs
typedef __attribute__((ext_vector_type(4))) float f32x4;    // MFMA accumulator

// ---------------- helpers ----------------

__device__ __forceinline__ short f2bf(float f){
  union { float f; unsigned u; } x; x.f = f;
  unsigned r = (x.u + 0x7FFFu + ((x.u >> 16) & 1u)) >> 16;  // RNE
  return (short)r;
}

__device__ __forceinline__ float gelu_f(float v){
  return 0.5f * v * (1.0f + erff(v * 0.70710678118654752f));
}

__device__ __forceinline__ float red16(float s){
  s += __shfl_xor(s, 1);
  s += __shfl_xor(s, 2);
  s += __shfl_xor(s, 4);
  s += __shfl_xor(s, 8);
  return s;
}

// A fragment for mfma_f32_16x16x32_bf16: lane holds A[row=lane&15][k = kq..kq+7]
// (kq = k0 + (lane>>4)*8). Reads 8 consecutive f32, converts to bf16.
__device__ __forceinline__ bf16x8 load_afrag(const float* __restrict__ src, int row, int kq, bool valid){
  bf16x8 a;
  if (valid){
    float4 v0 = *(const float4*)(src + (size_t)row * HH + kq);
    float4 v1 = *(const float4*)(src + (size_t)row * HH + kq + 4);
    a[0]=f2bf(v0.x); a[1]=f2bf(v0.y); a[2]=f2bf(v0.z); a[3]=f2bf(v0.w);
    a[4]=f2bf(v1.x); a[5]=f2bf(v1.y); a[6]=f2bf(v1.z); a[7]=f2bf(v1.w);
  } else {
    #pragma unroll
    for (int i = 0; i < 8; ++i) a[i] = 0;
  }
  return a;
}

// One K=64 GEMM phase: acc[ct] += A(src rows, cols col_off..col_off+63) x B (N=64, frag-major)
__device__ __forceinline__ void mfma_phase64(const float* __restrict__ src, int arow, bool valid,
    int col_off, const short* __restrict__ Bp, f32x4* acc, int lr, int q){
  #pragma unroll
  for (int kc = 0; kc < 2; ++kc){
    int kq = col_off + kc*32 + q*8;
    int kb = kc*4 + q;
    bf16x8 a = load_afrag(src, arow, kq, valid);
    #pragma unroll
    for (int ct = 0; ct < 4; ++ct){
      bf16x8 b = *(const bf16x8*)(Bp + (size_t)(kb*64 + ct*16 + lr)*8);
      acc[ct] = __builtin_amdgcn_mfma_f32_16x16x32_bf16(a, b, acc[ct], 0, 0, 0);
    }
  }
}

// relu + LayerNorm epilogue for MFMA layout: lane (lr,q) holds, for i=0..3,
// row = base_row+4q+i, cols {ct*16+lr} (P) and {64+ct*16+lr} (N).
__device__ __forceinline__ void ln_epi(f32x4* accP, f32x4* accN,
    const float* __restrict__ biasP, const float* __restrict__ biasN,
    const float* __restrict__ g, const float* __restrict__ b,
    float* __restrict__ out, int base_row, int lr, int q)
{
  float bp[4], bn[4], gp[4], gn[4], b0p[4], b0n[4];
  #pragma unroll
  for (int ct = 0; ct < 4; ++ct){
    int c = ct*16 + lr;
    bp[ct] = biasP[c];  bn[ct] = biasN[c];
    gp[ct] = g[c];      gn[ct] = g[64 + c];
    b0p[ct] = b[c];     b0n[ct] = b[64 + c];
  }
  #pragma unroll
  for (int i = 0; i < 4; ++i){
    int node = base_row + 4*q + i;
    float vP[4], vN[4];
    float s = 0.f;
    #pragma unroll
    for (int ct = 0; ct < 4; ++ct){
      vP[ct] = fmaxf(accP[ct][i] + bp[ct], 0.f);
      vN[ct] = fmaxf(accN[ct][i] + bn[ct], 0.f);
      s += vP[ct] + vN[ct];
    }
    s = red16(s);                      // 16-lane group = one row's 128 cols
    float mu = s * (1.0f / 128.0f);
    float q2 = 0.f;
    #pragma unroll
    for (int ct = 0; ct < 4; ++ct){
      float dP = vP[ct] - mu, dN = vN[ct] - mu;
      q2 += dP*dP + dN*dN;
    }
    q2 = red16(q2);
    float rstd = rsqrtf(q2 * (1.0f / 128.0f) + 1e-5f);
    if (node < NN){
      #pragma unroll
      for (int ct = 0; ct < 4; ++ct){
        int c = ct*16 + lr;
        out[(size_t)node * HH + c]      = (vP[ct] - mu) * rstd * gp[ct] + b0p[ct];
        out[(size_t)node * HH + 64 + c] = (vN[ct] - mu) * rstd * gn[ct] + b0n[ct];
      }
    }
  }
}

// ---------------- CSR build ----------------

__global__ void hist_kernel(const int* __restrict__ pe, const int* __restrict__ ne,
                            int* __restrict__ cnt_p, int* __restrict__ cnt_n){
  int t = blockIdx.x * 256 + threadIdx.x;
  if (t < EE)            atomicAdd(&cnt_p[pe[EE + t]], 1);
  else if (t < 2 * EE)   atomicAdd(&cnt_n[ne[EE + (t - EE)]], 1);
}

__global__ void scan1_kernel(const int* __restrict__ cnt_p, const int* __restrict__ cnt_n,
                             int* __restrict__ off_p, int* __restrict__ off_n,
                             int* __restrict__ parts){
  __shared__ int sh[256];
  const int arr = blockIdx.y;
  const int* cnt = arr ? cnt_n : cnt_p;
  int* off = arr ? off_n : off_p;
  const int b = blockIdx.x, t = threadIdx.x;
  const int base = b * 1024 + t * 4;
  int4 v = make_int4(0, 0, 0, 0);
  if (base + 3 < NN) v = *(const int4*)(cnt + base);
  else {
    if (base + 0 < NN) v.x = cnt[base + 0];
    if (base + 1 < NN) v.y = cnt[base + 1];
    if (base + 2 < NN) v.z = cnt[base + 2];
  }
  int s = v.x + v.y + v.z + v.w;
  sh[t] = s; __syncthreads();
  for (int d = 1; d < 256; d <<= 1){
    int tv = (t >= d) ? sh[t - d] : 0;
    __syncthreads();
    sh[t] += tv;
    __syncthreads();
  }
  int excl = sh[t] - s;
  if (base + 0 < NN) off[base + 0] = excl;
  if (base + 1 < NN) off[base + 1] = excl + v.x;
  if (base + 2 < NN) off[base + 2] = excl + v.x + v.y;
  if (base + 3 < NN) off[base + 3] = excl + v.x + v.y + v.z;
  if (t == 255) parts[arr * 128 + b] = sh[255];
}

__global__ void scan2_kernel(int* __restrict__ parts){
  int t = threadIdx.x;
  if (t < 2){
    int run = 0;
    for (int b = 0; b < 98; ++b){ int v = parts[t * 128 + b]; parts[t * 128 + b] = run; run += v; }
  }
}

__global__ void scan3_kernel(const int* __restrict__ parts,
                             const int* __restrict__ cnt_p, const int* __restrict__ cnt_n,
                             int* __restrict__ off_p, int* __restrict__ off_n,
                             int* __restrict__ cur_p, int* __restrict__ cur_n,
                             float* __restrict__ rp, float* __restrict__ rn){
  const int arr = blockIdx.y;
  int i = blockIdx.x * 256 + threadIdx.x;
  if (i < NN){
    if (arr == 0){
      int o = off_p[i] + parts[i >> 10];
      off_p[i] = o; cur_p[i] = o;
      rp[i] = 1.0f / fmaxf((float)cnt_p[i], 1.0f);
    } else {
      int o = off_n[i] + parts[128 + (i >> 10)];
      off_n[i] = o; cur_n[i] = o;
      rn[i] = 1.0f / fmaxf((float)cnt_n[i], 1.0f);
    }
  }
  if (blockIdx.x == 0 && threadIdx.x == 0){
    if (arr == 0) off_p[NN] = EE; else off_n[NN] = EE;
  }
}

__global__ void scatter_kernel(const int* __restrict__ pe, const int* __restrict__ ne,
                               int* __restrict__ cur_p, int* __restrict__ cur_n,
                               int* __restrict__ srcp, int* __restrict__ srcn){
  int t = blockIdx.x * 256 + threadIdx.x;
  if (t < EE){
    int p = atomicAdd(&cur_p[pe[EE + t]], 1);
    srcp[p] = pe[t];
  } else if (t < 2 * EE){
    int u = t - EE;
    int p = atomicAdd(&cur_n[ne[EE + u]], 1);
    srcn[p] = ne[u];
  }
}

// ---------------- aggregation (gather, 8 edges in flight) ----------------

__global__ __launch_bounds__(256) void agg_gather_kernel(const float* __restrict__ feat,
    const int* __restrict__ srcp, const int* __restrict__ srcn,
    const int* __restrict__ off_p, const int* __restrict__ off_n,
    const float* __restrict__ rp, const float* __restrict__ rn,
    float* __restrict__ sp, float* __restrict__ sn){
  int wid  = (blockIdx.x * 256 + threadIdx.x) >> 6;
  int lane = threadIdx.x & 63;
  if (wid >= 2 * NN) return;
  int nidx; const int* srcl; const int* off; const float* rcp; float* outp;
  if (wid < NN){ nidx = wid;      srcl = srcp; off = off_p; rcp = rp; outp = sp; }
  else         { nidx = wid - NN; srcl = srcn; off = off_n; rcp = rn; outp = sn; }
  int j = off[nidx], e = off[nidx + 1];
  const int fo = lane * 2;
  float ax[8], ay[8];
  #pragma unroll
  for (int i = 0; i < 8; ++i){ ax[i] = 0.f; ay[i] = 0.f; }
  for (; j + 7 < e; j += 8){
    #pragma unroll
    for (int i = 0; i < 8; ++i){
      int s = srcl[j + i];
      float2 v = *(const float2*)(feat + (size_t)s * HH + fo);
      ax[i] += v.x; ay[i] += v.y;
    }
  }
  if (j + 3 < e){
    #pragma unroll
    for (int i = 0; i < 4; ++i){
      int s = srcl[j + i];
      float2 v = *(const float2*)(feat + (size_t)s * HH + fo);
      ax[i] += v.x; ay[i] += v.y;
    }
    j += 4;
  }
  if (j + 1 < e){
    #pragma unroll
    for (int i = 0; i < 2; ++i){
      int s = srcl[j + i];
      float2 v = *(const float2*)(feat + (size_t)s * HH + fo);
      ax[i] += v.x; ay[i] += v.y;
    }
    j += 2;
  }
  if (j < e){
    int s = srcl[j];
    float2 v = *(const float2*)(feat + (size_t)s * HH + fo);
    ax[0] += v.x; ay[0] += v.y;
  }
  float r = rcp[nidx];
  float2 o;
  o.x = (((ax[0]+ax[1])+(ax[2]+ax[3])) + ((ax[4]+ax[5])+(ax[6]+ax[7]))) * r;
  o.y = (((ay[0]+ay[1])+(ay[2]+ay[3])) + ((ay[4]+ay[5])+(ay[6]+ay[7]))) * r;
  *(float2*)(outp + (size_t)nidx * HH + fo) = o;
}

// ---------------- weight prep: transpose + bf16 + MFMA-fragment-major ----------------
// Bp layout per region: [K/8][N][8] bf16 so a lane's B-fragment (8 k for one col) is 16B.

__global__ void prep_kernel(const float* __restrict__ c0_pl, const float* __restrict__ c0_pr,
                            const float* __restrict__ c0_nl, const float* __restrict__ c0_nr,
                            const float* __restrict__ c1_pl, const float* __restrict__ c1_pr,
                            const float* __restrict__ c1_nl, const float* __restrict__ c1_nr,
                            const float* __restrict__ pw1, const float* __restrict__ pw2,
                            short* __restrict__ WTb){
  int t = blockIdx.x * 256 + threadIdx.x;
  if (t >= 90112) return;
  int rb, N, k, j; float val;
  if (t < 8192){        rb = 0;     N = 64;  int u = t;         k = u >> 6; j = u & 63;  val = c0_pl[j*128 + k]; }
  else if (t < 16384){  rb = 8192;  N = 64;  int u = t - 8192;  k = u >> 6; j = u & 63;  val = c0_nl[j*128 + k]; }
  else if (t < 32768){  rb = 16384; N = 128; int u = t - 16384; k = u >> 7; j = u & 127;
                        val = (j < 64) ? c0_pr[j*128 + k] : c0_nr[(j-64)*128 + k]; }
  else if (t < 36864){  rb = 32768; N = 64;  int u = t - 32768; k = u >> 6; j = u & 63;  val = c1_pl[j*128 + k]; }
  else if (t < 40960){  rb = 36864; N = 64;  int u = t - 36864; k = u >> 6; j = u & 63;  val = c1_nl[j*128 + k]; }
  else if (t < 45056){  rb = 40960; N = 64;  int u = t - 40960; k = u >> 6; j = u & 63;  val = c1_nl[j*128 + 64 + k]; }
  else if (t < 49152){  rb = 45056; N = 64;  int u = t - 45056; k = u >> 6; j = u & 63;  val = c1_pl[j*128 + 64 + k]; }
  else if (t < 53248){  rb = 49152; N = 64;  int u = t - 49152; k = u >> 6; j = u & 63;  val = c1_pr[j*64 + k]; }
  else if (t < 57344){  rb = 53248; N = 64;  int u = t - 53248; k = u >> 6; j = u & 63;  val = c1_nr[j*64 + k]; }
  else if (t < 73728){  rb = 57344; N = 128; int u = t - 57344; k = u >> 7; j = u & 127; val = pw1[j*128 + k]; }
  else {                rb = 73728; N = 128; int u = t - 73728; k = u >> 7; j = u & 127; val = pw2[j*128 + k]; }
  WTb[rb + ((k >> 3) * N + j) * 8 + (k & 7)] = f2bf(val);
}

// ---------------- fused conv+relu+LN layers (MFMA, no LDS) ----------------

__global__ __launch_bounds__(256) void l0_kernel(
    const float* __restrict__ x, const float* __restrict__ sp, const float* __restrict__ sn,
    const short* __restrict__ WTb,
    const float* __restrict__ biasP, const float* __restrict__ biasN,
    const float* __restrict__ lng, const float* __restrict__ lnb,
    float* __restrict__ h0)
{
  const int l = threadIdx.x & 63, w = threadIdx.x >> 6;
  const int lr = l & 15, q = l >> 4;
  const int base_row = (blockIdx.x << 6) + (w << 4);
  const int arow = base_row + lr;
  const bool valid = arow < NN;
  f32x4 accP[4], accN[4];
  #pragma unroll
  for (int ct = 0; ct < 4; ++ct)
    #pragma unroll
    for (int i = 0; i < 4; ++i){ accP[ct][i] = 0.f; accN[ct][i] = 0.f; }

  // phase 1+2: ap @ c0_pl^T -> P ; an @ c0_nl^T -> N (K=128 each)
  mfma_phase64(sp, arow, valid, 0,  WTb + 0,    accP, lr, q);
  mfma_phase64(sp, arow, valid, 64, WTb + 4096, accP, lr, q);   // second K-half of region 0
  mfma_phase64(sn, arow, valid, 0,  WTb + 8192, accN, lr, q);
  mfma_phase64(sn, arow, valid, 64, WTb + 12288, accN, lr, q);
  // phase 3: x @ [c0_pr^T | c0_nr^T] (K=128, N=128)
  #pragma unroll
  for (int kc = 0; kc < 4; ++kc){
    int kq = kc*32 + q*8, kb = kc*4 + q;
    bf16x8 a = load_afrag(x, arow, kq, valid);
    #pragma unroll
    for (int ct = 0; ct < 4; ++ct){
      bf16x8 bp = *(const bf16x8*)(WTb + 16384 + (size_t)(kb*128 + ct*16 + lr)*8);
      bf16x8 bn = *(const bf16x8*)(WTb + 16384 + (size_t)(kb*128 + 64 + ct*16 + lr)*8);
      accP[ct] = __builtin_amdgcn_mfma_f32_16x16x32_bf16(a, bp, accP[ct], 0, 0, 0);
      accN[ct] = __builtin_amdgcn_mfma_f32_16x16x32_bf16(a, bn, accN[ct], 0, 0, 0);
    }
  }
  ln_epi(accP, accN, biasP, biasN, lng, lnb, h0, base_row, lr, q);
}

__global__ __launch_bounds__(256) void l1_kernel(
    const float* __restrict__ h0, const float* __restrict__ sp, const float* __restrict__ sn,
    const short* __restrict__ WTb,
    const float* __restrict__ biasP, const float* __restrict__ biasN,
    const float* __restrict__ lng, const float* __restrict__ lnb,
    float* __restrict__ h1)
{
  const int l = threadIdx.x & 63, w = threadIdx.x >> 6;
  const int lr = l & 15, q = l >> 4;
  const int base_row = (blockIdx.x << 6) + (w << 4);
  const int arow = base_row + lr;
  const bool valid = arow < NN;
  f32x4 accP[4], accN[4];
  #pragma unroll
  for (int ct = 0; ct < 4; ++ct)
    #pragma unroll
    for (int i = 0; i < 4; ++i){ accP[ct][i] = 0.f; accN[ct][i] = 0.f; }

  // sp = [aggP(xp)|aggP(xn)], sn = [aggN(xp)|aggN(xn)]  (K=64 per phase)
  mfma_phase64(sp, arow, valid, 0,  WTb + 32768, accP, lr, q);  // aggP(xp) @ c1_pl[:,:64]^T
  mfma_phase64(sp, arow, valid, 64, WTb + 36864, accN, lr, q);  // aggP(xn) @ c1_nl[:,:64]^T
  mfma_phase64(sn, arow, valid, 0,  WTb + 40960, accN, lr, q);  // aggN(xp) @ c1_nl[:,64:]^T
  mfma_phase64(sn, arow, valid, 64, WTb + 45056, accP, lr, q);  // aggN(xn) @ c1_pl[:,64:]^T
  mfma_phase64(h0, arow, valid, 0,  WTb + 49152, accP, lr, q);  // xp @ c1_pr^T
  mfma_phase64(h0, arow, valid, 64, WTb + 53248, accN, lr, q);  // xn @ c1_nr^T

  // h1 may alias sp: this wave read only its own rows above (loads complete
  // before dependent mfma, which precede these stores); no cross-wave sharing.
  ln_epi(accP, accN, biasP, biasN, lng, lnb, h1, base_row, lr, q);
}

__global__ __launch_bounds__(256) void mlp_kernel(
    const float* __restrict__ h1, const float* __restrict__ x0,
    const short* __restrict__ WTb, const float* __restrict__ pb1, const float* __restrict__ pb2,
    const float* __restrict__ gate, float* __restrict__ out)
{
  __shared__ __align__(16) short T[64 * 136];   // gelu intermediate, bf16, pad->2-way-free
  const int l = threadIdx.x & 63, w = threadIdx.x >> 6;
  const int lr = l & 15, q = l >> 4;
  const int base_row = (blockIdx.x << 6) + (w << 4);
  const int arow = base_row + lr;
  const bool valid = arow < NN;
  f32x4 accP[4], accN[4];
  #pragma unroll
  for (int ct = 0; ct < 4; ++ct)
    #pragma unroll
    for (int i = 0; i < 4; ++i){ accP[ct][i] = 0.f; accN[ct][i] = 0.f; }

  // GEMM1: h1 @ pw1^T (K=128, N=128)
  #pragma unroll
  for (int kc = 0; kc < 4; ++kc){
    int kq = kc*32 + q*8, kb = kc*4 + q;
    bf16x8 a = load_afrag(h1, arow, kq, valid);
    #pragma unroll
    for (int ct = 0; ct < 4; ++ct){
      bf16x8 bp = *(const bf16x8*)(WTb + 57344 + (size_t)(kb*128 + ct*16 + lr)*8);
      bf16x8 bn = *(const bf16x8*)(WTb + 57344 + (size_t)(kb*128 + 64 + ct*16 + lr)*8);
      accP[ct] = __builtin_amdgcn_mfma_f32_16x16x32_bf16(a, bp, accP[ct], 0, 0, 0);
      accN[ct] = __builtin_amdgcn_mfma_f32_16x16x32_bf16(a, bn, accN[ct], 0, 0, 0);
    }
  }
  // gelu -> T (bf16)
  #pragma unroll
  for (int ct = 0; ct < 4; ++ct){
    int c = ct*16 + lr;
    float p1p = pb1[c], p1n = pb1[64 + c];
    #pragma unroll
    for (int i = 0; i < 4; ++i){
      int r = (w << 4) + 4*q + i;
      T[r*136 + c]      = f2bf(gelu_f(accP[ct][i] + p1p));
      T[r*136 + 64 + c] = f2bf(gelu_f(accN[ct][i] + p1n));
    }
  }
  __syncthreads();
  // GEMM2: T @ pw2^T (K=128, N=128), A from LDS bf16
  f32x4 aP[4], aN[4];
  #pragma unroll
  for (int ct = 0; ct < 4; ++ct)
    #pragma unroll
    for (int i = 0; i < 4; ++i){ aP[ct][i] = 0.f; aN[ct][i] = 0.f; }
  const int trow = (w << 4) + lr;
  #pragma unroll
  for (int kc = 0; kc < 4; ++kc){
    int kq = kc*32 + q*8, kb = kc*4 + q;
    bf16x8 a = *(const bf16x8*)(&T[trow*136 + kq]);
    #pragma unroll
    for (int ct = 0; ct < 4; ++ct){
      bf16x8 bp = *(const bf16x8*)(WTb + 73728 + (size_t)(kb*128 + ct*16 + lr)*8);
      bf16x8 bn = *(const bf16x8*)(WTb + 73728 + (size_t)(kb*128 + 64 + ct*16 + lr)*8);
      aP[ct] = __builtin_amdgcn_mfma_f32_16x16x32_bf16(a, bp, aP[ct], 0, 0, 0);
      aN[ct] = __builtin_amdgcn_mfma_f32_16x16x32_bf16(a, bn, aN[ct], 0, 0, 0);
    }
  }
  // epilogue: gated residual
  float gt = gate[0], og = 1.0f - gt;
  #pragma unroll
  for (int i = 0; i < 4; ++i){
    int node = base_row + 4*q + i;
    if (node < NN){
      #pragma unroll
      for (int ct = 0; ct < 4; ++ct){
        int c = ct*16 + lr;
        out[(size_t)node*HH + c]      = gt*(aP[ct][i] + pb2[c])      + og*x0[(size_t)node*HH + c];
        out[(size_t)node*HH + 64 + c] = gt*(aN[ct][i] + pb2[64 + c]) + og*x0[(size_t)node*HH + 64 + c];
      }
    }
  }
}

// ---------------- launch ----------------

extern "C" void kernel_launch(void* const* d_in, const int* in_sizes, int n_in,
                              void* d_out, int out_size, void* d_ws, size_t ws_size,
                              hipStream_t stream){
  (void)in_sizes; (void)n_in; (void)out_size;
  const float* x     = (const float*)d_in[0];
  const int*   pe    = (const int*)d_in[1];
  const int*   ne    = (const int*)d_in[2];
  const float* c0_pl = (const float*)d_in[3];
  const float* c0_pr = (const float*)d_in[4];
  const float* c0_pr_b = (const float*)d_in[5];
  const float* c0_nl = (const float*)d_in[6];
  const float* c0_nr = (const float*)d_in[7];
  const float* c0_nr_b = (const float*)d_in[8];
  const float* c1_pl = (const float*)d_in[9];
  const float* c1_pr = (const float*)d_in[10];
  const float* c1_pr_b = (const float*)d_in[11];
  const float* c1_nl = (const float*)d_in[12];
  const float* c1_nr = (const float*)d_in[13];
  const float* c1_nr_b = (const float*)d_in[14];
  const float* ln0_g = (const float*)d_in[15];
  const float* ln0_b = (const float*)d_in[16];
  const float* ln1_g = (const float*)d_in[17];
  const float* ln1_b = (const float*)d_in[18];
  const float* pw1   = (const float*)d_in[19];
  const float* pb1   = (const float*)d_in[20];
  const float* pw2   = (const float*)d_in[21];
  const float* pb2   = (const float*)d_in[22];
  const float* gate  = (const float*)d_in[23];
  float* out = (float*)d_out;
  float* ws  = (float*)d_ws;

  // Workspace layout. h0 lives in d_out; h1 aliases s_pos (wave-local rows, see l1).
  float* s_pos = ws;                                   // N*128 (then h1)
  float* s_neg = ws + (size_t)NN * HH;                 // N*128
  float* rp    = ws + (size_t)2 * NN * HH;             // N
  float* rn    = rp + NN;                              // N
  short* WTb   = (short*)(rn + NN);                    // 90112 bf16 (16B-aligned)
  int* cnt_p = (int*)((char*)WTb + 90112 * sizeof(short)); // N
  int* cnt_n = cnt_p + NN;                             // N
  int* off_p = cnt_n + NN;                             // N+1
  int* off_n = off_p + NN + 1;                         // N+1
  int* cur_p = off_n + NN + 1;                         // N
  int* cur_n = cur_p + NN;                             // N
  int* parts = cur_n + NN;                             // 256
  int* srcp  = parts + 256;                            // E
  int* srcn  = srcp + EE;                              // E
  const size_t need = (size_t)((char*)(srcn + EE) - (char*)ws);
  if (ws_size < need) return;  // defensive: never scribble OOB

  hipMemsetAsync(cnt_p, 0, (size_t)2 * NN * sizeof(int), stream);
  prep_kernel<<<352, 256, 0, stream>>>(c0_pl, c0_pr, c0_nl, c0_nr,
                                       c1_pl, c1_pr, c1_nl, c1_nr, pw1, pw2, WTb);
  hist_kernel<<<(2 * EE) / 256, 256, 0, stream>>>(pe, ne, cnt_p, cnt_n);
  scan1_kernel<<<dim3(98, 2), 256, 0, stream>>>(cnt_p, cnt_n, off_p, off_n, parts);
  scan2_kernel<<<1, 64, 0, stream>>>(parts);
  scan3_kernel<<<dim3(391, 2), 256, 0, stream>>>(parts, cnt_p, cnt_n, off_p, off_n,
                                                 cur_p, cur_n, rp, rn);
  scatter_kernel<<<(2 * EE) / 256, 256, 0, stream>>>(pe, ne, cur_p, cur_n, srcp, srcn);

  // layer 0
  agg_gather_kernel<<<(2 * NN * 64) / 256, 256, 0, stream>>>(x, srcp, srcn, off_p, off_n,
                                                             rp, rn, s_pos, s_neg);
  l0_kernel<<<(NN + 63) / 64, 256, 0, stream>>>(x, s_pos, s_neg, WTb,
                                                c0_pr_b, c0_nr_b, ln0_g, ln0_b, out /*h0*/);
  // layer 1 (reuse CSR)
  agg_gather_kernel<<<(2 * NN * 64) / 256, 256, 0, stream>>>(out /*h0*/, srcp, srcn, off_p, off_n,
                                                             rp, rn, s_pos, s_neg);
  l1_kernel<<<(NN + 63) / 64, 256, 0, stream>>>(out /*h0*/, s_pos, s_neg, WTb,
                                                c1_pr_b, c1_nr_b, ln1_g, ln1_b, s_pos /*h1*/);
  // MLP + gated residual
  mlp_kernel<<<(NN + 63) / 64, 256, 0, stream>>>(s_pos /*h1*/, x, WTb, pb1, pb2, gate, out);
}

// Round 10
// 605.308 us; speedup vs baseline: 5.2020x; 1.1766x over previous
//
#include <hip/hip_runtime.h>
#include <cstddef>

#define NN 100000
#define HH 128
#define EE 800000

typedef __attribute__((ext_vector_type(8))) short bf16x8;   // 8 bf16 = 4 VGPRs
typedef __attribute__((ext_vector_type(4))) float f32x4;    // MFMA accumulator

// ---------------- helpers ----------------

__device__ __forceinline__ short f2bf(float f){
  union { float f; unsigned u; } x; x.f = f;
  unsigned r = (x.u + 0x7FFFu + ((x.u >> 16) & 1u)) >> 16;  // RNE
  return (short)r;
}

__device__ __forceinline__ float bf2f(unsigned short us){
  union { unsigned u; float f; } t; t.u = (unsigned)us << 16; return t.f;
}

__device__ __forceinline__ float gelu_f(float v){
  return 0.5f * v * (1.0f + erff(v * 0.70710678118654752f));
}

__device__ __forceinline__ float red16(float s){
  s += __shfl_xor(s, 1);
  s += __shfl_xor(s, 2);
  s += __shfl_xor(s, 4);
  s += __shfl_xor(s, 8);
  return s;
}

// A fragment from a bf16 row-major [*, 128] array: lane holds A[row][kq..kq+7].
__device__ __forceinline__ bf16x8 load_afrag_bf(const short* __restrict__ src, int row, int kq, bool valid){
  if (valid) return *(const bf16x8*)(src + (size_t)row * HH + kq);
  bf16x8 z;
  #pragma unroll
  for (int i = 0; i < 8; ++i) z[i] = 0;
  return z;
}

// One K=64 GEMM phase: acc[ct] += A(bf16 src rows, cols col_off..+63) x B (N=64, frag-major)
__device__ __forceinline__ void mfma_phase64(const short* __restrict__ src, int arow, bool valid,
    int col_off, const short* __restrict__ Bp, f32x4* acc, int lr, int q){
  #pragma unroll
  for (int kc = 0; kc < 2; ++kc){
    int kq = col_off + kc*32 + q*8;
    int kb = kc*4 + q;
    bf16x8 a = load_afrag_bf(src, arow, kq, valid);
    #pragma unroll
    for (int ct = 0; ct < 4; ++ct){
      bf16x8 b = *(const bf16x8*)(Bp + (size_t)(kb*64 + ct*16 + lr)*8);
      acc[ct] = __builtin_amdgcn_mfma_f32_16x16x32_bf16(a, b, acc[ct], 0, 0, 0);
    }
  }
}

// relu + LayerNorm epilogue; writes bf16 output rows.
__device__ __forceinline__ void ln_epi(f32x4* accP, f32x4* accN,
    const float* __restrict__ biasP, const float* __restrict__ biasN,
    const float* __restrict__ g, const float* __restrict__ b,
    short* __restrict__ out, int base_row, int lr, int q)
{
  float bp[4], bn[4], gp[4], gn[4], b0p[4], b0n[4];
  #pragma unroll
  for (int ct = 0; ct < 4; ++ct){
    int c = ct*16 + lr;
    bp[ct] = biasP[c];  bn[ct] = biasN[c];
    gp[ct] = g[c];      gn[ct] = g[64 + c];
    b0p[ct] = b[c];     b0n[ct] = b[64 + c];
  }
  #pragma unroll
  for (int i = 0; i < 4; ++i){
    int node = base_row + 4*q + i;
    float vP[4], vN[4];
    float s = 0.f;
    #pragma unroll
    for (int ct = 0; ct < 4; ++ct){
      vP[ct] = fmaxf(accP[ct][i] + bp[ct], 0.f);
      vN[ct] = fmaxf(accN[ct][i] + bn[ct], 0.f);
      s += vP[ct] + vN[ct];
    }
    s = red16(s);                      // 16-lane group = one row's 128 cols
    float mu = s * (1.0f / 128.0f);
    float q2 = 0.f;
    #pragma unroll
    for (int ct = 0; ct < 4; ++ct){
      float dP = vP[ct] - mu, dN = vN[ct] - mu;
      q2 += dP*dP + dN*dN;
    }
    q2 = red16(q2);
    float rstd = rsqrtf(q2 * (1.0f / 128.0f) + 1e-5f);
    if (node < NN){
      #pragma unroll
      for (int ct = 0; ct < 4; ++ct){
        int c = ct*16 + lr;
        out[(size_t)node * HH + c]      = f2bf((vP[ct] - mu) * rstd * gp[ct] + b0p[ct]);
        out[(size_t)node * HH + 64 + c] = f2bf((vN[ct] - mu) * rstd * gn[ct] + b0n[ct]);
      }
    }
  }
}

// ---------------- x -> bf16 convert ----------------

__global__ void cvt_kernel(const float* __restrict__ in, short* __restrict__ outb){
  int i = blockIdx.x * 256 + threadIdx.x;
  if (i >= (NN * HH) / 8) return;
  const float4* p = (const float4*)(in + (size_t)i * 8);
  float4 v0 = p[0], v1 = p[1];
  bf16x8 o;
  o[0]=f2bf(v0.x); o[1]=f2bf(v0.y); o[2]=f2bf(v0.z); o[3]=f2bf(v0.w);
  o[4]=f2bf(v1.x); o[5]=f2bf(v1.y); o[6]=f2bf(v1.z); o[7]=f2bf(v1.w);
  *(bf16x8*)(outb + (size_t)i * 8) = o;
}

// ---------------- CSR build ----------------

__global__ void hist_kernel(const int* __restrict__ pe, const int* __restrict__ ne,
                            int* __restrict__ cnt_p, int* __restrict__ cnt_n){
  int t = blockIdx.x * 256 + threadIdx.x;
  if (t < EE)            atomicAdd(&cnt_p[pe[EE + t]], 1);
  else if (t < 2 * EE)   atomicAdd(&cnt_n[ne[EE + (t - EE)]], 1);
}

__global__ void scan1_kernel(const int* __restrict__ cnt_p, const int* __restrict__ cnt_n,
                             int* __restrict__ off_p, int* __restrict__ off_n,
                             int* __restrict__ parts){
  __shared__ int sh[256];
  const int arr = blockIdx.y;
  const int* cnt = arr ? cnt_n : cnt_p;
  int* off = arr ? off_n : off_p;
  const int b = blockIdx.x, t = threadIdx.x;
  const int base = b * 1024 + t * 4;
  int4 v = make_int4(0, 0, 0, 0);
  if (base + 3 < NN) v = *(const int4*)(cnt + base);
  else {
    if (base + 0 < NN) v.x = cnt[base + 0];
    if (base + 1 < NN) v.y = cnt[base + 1];
    if (base + 2 < NN) v.z = cnt[base + 2];
  }
  int s = v.x + v.y + v.z + v.w;
  sh[t] = s; __syncthreads();
  for (int d = 1; d < 256; d <<= 1){
    int tv = (t >= d) ? sh[t - d] : 0;
    __syncthreads();
    sh[t] += tv;
    __syncthreads();
  }
  int excl = sh[t] - s;
  if (base + 0 < NN) off[base + 0] = excl;
  if (base + 1 < NN) off[base + 1] = excl + v.x;
  if (base + 2 < NN) off[base + 2] = excl + v.x + v.y;
  if (base + 3 < NN) off[base + 3] = excl + v.x + v.y + v.z;
  if (t == 255) parts[arr * 128 + b] = sh[255];
}

__global__ void scan2_kernel(int* __restrict__ parts){
  int t = threadIdx.x;
  if (t < 2){
    int run = 0;
    for (int b = 0; b < 98; ++b){ int v = parts[t * 128 + b]; parts[t * 128 + b] = run; run += v; }
  }
}

__global__ void scan3_kernel(const int* __restrict__ parts,
                             const int* __restrict__ cnt_p, const int* __restrict__ cnt_n,
                             int* __restrict__ off_p, int* __restrict__ off_n,
                             int* __restrict__ cur_p, int* __restrict__ cur_n,
                             float* __restrict__ rp, float* __restrict__ rn){
  const int arr = blockIdx.y;
  int i = blockIdx.x * 256 + threadIdx.x;
  if (i < NN){
    if (arr == 0){
      int o = off_p[i] + parts[i >> 10];
      off_p[i] = o; cur_p[i] = o;
      rp[i] = 1.0f / fmaxf((float)cnt_p[i], 1.0f);
    } else {
      int o = off_n[i] + parts[128 + (i >> 10)];
      off_n[i] = o; cur_n[i] = o;
      rn[i] = 1.0f / fmaxf((float)cnt_n[i], 1.0f);
    }
  }
  if (blockIdx.x == 0 && threadIdx.x == 0){
    if (arr == 0) off_p[NN] = EE; else off_n[NN] = EE;
  }
}

__global__ void scatter_kernel(const int* __restrict__ pe, const int* __restrict__ ne,
                               int* __restrict__ cur_p, int* __restrict__ cur_n,
                               int* __restrict__ srcp, int* __restrict__ srcn){
  int t = blockIdx.x * 256 + threadIdx.x;
  if (t < EE){
    int p = atomicAdd(&cur_p[pe[EE + t]], 1);
    srcp[p] = pe[t];
  } else if (t < 2 * EE){
    int u = t - EE;
    int p = atomicAdd(&cur_n[ne[EE + u]], 1);
    srcn[p] = ne[u];
  }
}

// ---------------- aggregation (bf16 gather, 8 edges in flight) ----------------
// feat rows are 128 bf16 (256 B). Lane handles 2 features = one u32 load/edge.

__global__ __launch_bounds__(256) void agg_gather_kernel(const short* __restrict__ feat,
    const int* __restrict__ srcp, const int* __restrict__ srcn,
    const int* __restrict__ off_p, const int* __restrict__ off_n,
    const float* __restrict__ rp, const float* __restrict__ rn,
    short* __restrict__ sp, short* __restrict__ sn){
  int wid  = (blockIdx.x * 256 + threadIdx.x) >> 6;
  int lane = threadIdx.x & 63;
  if (wid >= 2 * NN) return;
  int nidx; const int* srcl; const int* off; const float* rcp; short* outp;
  if (wid < NN){ nidx = wid;      srcl = srcp; off = off_p; rcp = rp; outp = sp; }
  else         { nidx = wid - NN; srcl = srcn; off = off_n; rcp = rn; outp = sn; }
  int j = off[nidx], e = off[nidx + 1];
  const int fo = lane * 2;   // shorts
  float ax[8], ay[8];
  #pragma unroll
  for (int i = 0; i < 8; ++i){ ax[i] = 0.f; ay[i] = 0.f; }
  for (; j + 7 < e; j += 8){
    #pragma unroll
    for (int i = 0; i < 8; ++i){
      int s = srcl[j + i];
      unsigned v = *(const unsigned*)(feat + (size_t)s * HH + fo);
      ax[i] += bf2f((unsigned short)(v & 0xffffu));
      ay[i] += bf2f((unsigned short)(v >> 16));
    }
  }
  if (j + 3 < e){
    #pragma unroll
    for (int i = 0; i < 4; ++i){
      int s = srcl[j + i];
      unsigned v = *(const unsigned*)(feat + (size_t)s * HH + fo);
      ax[i] += bf2f((unsigned short)(v & 0xffffu));
      ay[i] += bf2f((unsigned short)(v >> 16));
    }
    j += 4;
  }
  if (j + 1 < e){
    #pragma unroll
    for (int i = 0; i < 2; ++i){
      int s = srcl[j + i];
      unsigned v = *(const unsigned*)(feat + (size_t)s * HH + fo);
      ax[i] += bf2f((unsigned short)(v & 0xffffu));
      ay[i] += bf2f((unsigned short)(v >> 16));
    }
    j += 2;
  }
  if (j < e){
    int s = srcl[j];
    unsigned v = *(const unsigned*)(feat + (size_t)s * HH + fo);
    ax[0] += bf2f((unsigned short)(v & 0xffffu));
    ay[0] += bf2f((unsigned short)(v >> 16));
  }
  float r = rcp[nidx];
  float ox = (((ax[0]+ax[1])+(ax[2]+ax[3])) + ((ax[4]+ax[5])+(ax[6]+ax[7]))) * r;
  float oy = (((ay[0]+ay[1])+(ay[2]+ay[3])) + ((ay[4]+ay[5])+(ay[6]+ay[7]))) * r;
  unsigned ov = ((unsigned)(unsigned short)f2bf(oy) << 16) | (unsigned)(unsigned short)f2bf(ox);
  *(unsigned*)(outp + (size_t)nidx * HH + fo) = ov;
}

// ---------------- weight prep: transpose + bf16 + MFMA-fragment-major ----------------
// Bp layout per region: [K/8][N][8] bf16 so a lane's B-fragment (8 k for one col) is 16B.

__global__ void prep_kernel(const float* __restrict__ c0_pl, const float* __restrict__ c0_pr,
                            const float* __restrict__ c0_nl, const float* __restrict__ c0_nr,
                            const float* __restrict__ c1_pl, const float* __restrict__ c1_pr,
                            const float* __restrict__ c1_nl, const float* __restrict__ c1_nr,
                            const float* __restrict__ pw1, const float* __restrict__ pw2,
                            short* __restrict__ WTb){
  int t = blockIdx.x * 256 + threadIdx.x;
  if (t >= 90112) return;
  int rb, N, k, j; float val;
  if (t < 8192){        rb = 0;     N = 64;  int u = t;         k = u >> 6; j = u & 63;  val = c0_pl[j*128 + k]; }
  else if (t < 16384){  rb = 8192;  N = 64;  int u = t - 8192;  k = u >> 6; j = u & 63;  val = c0_nl[j*128 + k]; }
  else if (t < 32768){  rb = 16384; N = 128; int u = t - 16384; k = u >> 7; j = u & 127;
                        val = (j < 64) ? c0_pr[j*128 + k] : c0_nr[(j-64)*128 + k]; }
  else if (t < 36864){  rb = 32768; N = 64;  int u = t - 32768; k = u >> 6; j = u & 63;  val = c1_pl[j*128 + k]; }
  else if (t < 40960){  rb = 36864; N = 64;  int u = t - 36864; k = u >> 6; j = u & 63;  val = c1_nl[j*128 + k]; }
  else if (t < 45056){  rb = 40960; N = 64;  int u = t - 40960; k = u >> 6; j = u & 63;  val = c1_nl[j*128 + 64 + k]; }
  else if (t < 49152){  rb = 45056; N = 64;  int u = t - 45056; k = u >> 6; j = u & 63;  val = c1_pl[j*128 + 64 + k]; }
  else if (t < 53248){  rb = 49152; N = 64;  int u = t - 49152; k = u >> 6; j = u & 63;  val = c1_pr[j*64 + k]; }
  else if (t < 57344){  rb = 53248; N = 64;  int u = t - 53248; k = u >> 6; j = u & 63;  val = c1_nr[j*64 + k]; }
  else if (t < 73728){  rb = 57344; N = 128; int u = t - 57344; k = u >> 7; j = u & 127; val = pw1[j*128 + k]; }
  else {                rb = 73728; N = 128; int u = t - 73728; k = u >> 7; j = u & 127; val = pw2[j*128 + k]; }
  WTb[rb + ((k >> 3) * N + j) * 8 + (k & 7)] = f2bf(val);
}

// ---------------- fused conv+relu+LN layers (MFMA, bf16 I/O) ----------------

__global__ __launch_bounds__(256) void l0_kernel(
    const short* __restrict__ xb, const short* __restrict__ sp, const short* __restrict__ sn,
    const short* __restrict__ WTb,
    const float* __restrict__ biasP, const float* __restrict__ biasN,
    const float* __restrict__ lng, const float* __restrict__ lnb,
    short* __restrict__ h0)
{
  const int l = threadIdx.x & 63, w = threadIdx.x >> 6;
  const int lr = l & 15, q = l >> 4;
  const int base_row = (blockIdx.x << 6) + (w << 4);
  const int arow = base_row + lr;
  const bool valid = arow < NN;
  f32x4 accP[4], accN[4];
  #pragma unroll
  for (int ct = 0; ct < 4; ++ct)
    #pragma unroll
    for (int i = 0; i < 4; ++i){ accP[ct][i] = 0.f; accN[ct][i] = 0.f; }

  // phase 1+2: ap @ c0_pl^T -> P ; an @ c0_nl^T -> N (K=128 each)
  mfma_phase64(sp, arow, valid, 0,  WTb + 0,     accP, lr, q);
  mfma_phase64(sp, arow, valid, 64, WTb + 4096,  accP, lr, q);
  mfma_phase64(sn, arow, valid, 0,  WTb + 8192,  accN, lr, q);
  mfma_phase64(sn, arow, valid, 64, WTb + 12288, accN, lr, q);
  // phase 3: x @ [c0_pr^T | c0_nr^T] (K=128, N=128)
  #pragma unroll
  for (int kc = 0; kc < 4; ++kc){
    int kq = kc*32 + q*8, kb = kc*4 + q;
    bf16x8 a = load_afrag_bf(xb, arow, kq, valid);
    #pragma unroll
    for (int ct = 0; ct < 4; ++ct){
      bf16x8 bp = *(const bf16x8*)(WTb + 16384 + (size_t)(kb*128 + ct*16 + lr)*8);
      bf16x8 bn = *(const bf16x8*)(WTb + 16384 + (size_t)(kb*128 + 64 + ct*16 + lr)*8);
      accP[ct] = __builtin_amdgcn_mfma_f32_16x16x32_bf16(a, bp, accP[ct], 0, 0, 0);
      accN[ct] = __builtin_amdgcn_mfma_f32_16x16x32_bf16(a, bn, accN[ct], 0, 0, 0);
    }
  }
  ln_epi(accP, accN, biasP, biasN, lng, lnb, h0, base_row, lr, q);
}

__global__ __launch_bounds__(256) void l1_kernel(
    const short* __restrict__ h0, const short* __restrict__ sp, const short* __restrict__ sn,
    const short* __restrict__ WTb,
    const float* __restrict__ biasP, const float* __restrict__ biasN,
    const float* __restrict__ lng, const float* __restrict__ lnb,
    short* __restrict__ h1)
{
  const int l = threadIdx.x & 63, w = threadIdx.x >> 6;
  const int lr = l & 15, q = l >> 4;
  const int base_row = (blockIdx.x << 6) + (w << 4);
  const int arow = base_row + lr;
  const bool valid = arow < NN;
  f32x4 accP[4], accN[4];
  #pragma unroll
  for (int ct = 0; ct < 4; ++ct)
    #pragma unroll
    for (int i = 0; i < 4; ++i){ accP[ct][i] = 0.f; accN[ct][i] = 0.f; }

  // sp = [aggP(xp)|aggP(xn)], sn = [aggN(xp)|aggN(xn)]  (K=64 per phase)
  mfma_phase64(sp, arow, valid, 0,  WTb + 32768, accP, lr, q);  // aggP(xp) @ c1_pl[:,:64]^T
  mfma_phase64(sp, arow, valid, 64, WTb + 36864, accN, lr, q);  // aggP(xn) @ c1_nl[:,:64]^T
  mfma_phase64(sn, arow, valid, 0,  WTb + 40960, accN, lr, q);  // aggN(xp) @ c1_nl[:,64:]^T
  mfma_phase64(sn, arow, valid, 64, WTb + 45056, accP, lr, q);  // aggN(xn) @ c1_pl[:,64:]^T
  mfma_phase64(h0, arow, valid, 0,  WTb + 49152, accP, lr, q);  // xp @ c1_pr^T
  mfma_phase64(h0, arow, valid, 64, WTb + 53248, accN, lr, q);  // xn @ c1_nr^T

  // h1 may alias sp: wave read only its own rows above (loads complete before
  // dependent mfma, which precede these stores); no cross-wave sharing.
  ln_epi(accP, accN, biasP, biasN, lng, lnb, h1, base_row, lr, q);
}

__global__ __launch_bounds__(256) void mlp_kernel(
    const short* __restrict__ h1, const float* __restrict__ x0,
    const short* __restrict__ WTb, const float* __restrict__ pb1, const float* __restrict__ pb2,
    const float* __restrict__ gate, float* __restrict__ out)
{
  __shared__ __align__(16) short T[64 * 136];   // gelu intermediate, bf16
  const int l = threadIdx.x & 63, w = threadIdx.x >> 6;
  const int lr = l & 15, q = l >> 4;
  const int base_row = (blockIdx.x << 6) + (w << 4);
  const int arow = base_row + lr;
  const bool valid = arow < NN;
  f32x4 accP[4], accN[4];
  #pragma unroll
  for (int ct = 0; ct < 4; ++ct)
    #pragma unroll
    for (int i = 0; i < 4; ++i){ accP[ct][i] = 0.f; accN[ct][i] = 0.f; }

  // GEMM1: h1 @ pw1^T (K=128, N=128)
  #pragma unroll
  for (int kc = 0; kc < 4; ++kc){
    int kq = kc*32 + q*8, kb = kc*4 + q;
    bf16x8 a = load_afrag_bf(h1, arow, kq, valid);
    #pragma unroll
    for (int ct = 0; ct < 4; ++ct){
      bf16x8 bp = *(const bf16x8*)(WTb + 57344 + (size_t)(kb*128 + ct*16 + lr)*8);
      bf16x8 bn = *(const bf16x8*)(WTb + 57344 + (size_t)(kb*128 + 64 + ct*16 + lr)*8);
      accP[ct] = __builtin_amdgcn_mfma_f32_16x16x32_bf16(a, bp, accP[ct], 0, 0, 0);
      accN[ct] = __builtin_amdgcn_mfma_f32_16x16x32_bf16(a, bn, accN[ct], 0, 0, 0);
    }
  }
  // gelu -> T (bf16)
  #pragma unroll
  for (int ct = 0; ct < 4; ++ct){
    int c = ct*16 + lr;
    float p1p = pb1[c], p1n = pb1[64 + c];
    #pragma unroll
    for (int i = 0; i < 4; ++i){
      int r = (w << 4) + 4*q + i;
      T[r*136 + c]      = f2bf(gelu_f(accP[ct][i] + p1p));
      T[r*136 + 64 + c] = f2bf(gelu_f(accN[ct][i] + p1n));
    }
  }
  __syncthreads();
  // GEMM2: T @ pw2^T (K=128, N=128), A from LDS bf16
  f32x4 aP[4], aN[4];
  #pragma unroll
  for (int ct = 0; ct < 4; ++ct)
    #pragma unroll
    for (int i = 0; i < 4; ++i){ aP[ct][i] = 0.f; aN[ct][i] = 0.f; }
  const int trow = (w << 4) + lr;
  #pragma unroll
  for (int kc = 0; kc < 4; ++kc){
    int kq = kc*32 + q*8, kb = kc*4 + q;
    bf16x8 a = *(const bf16x8*)(&T[trow*136 + kq]);
    #pragma unroll
    for (int ct = 0; ct < 4; ++ct){
      bf16x8 bp = *(const bf16x8*)(WTb + 73728 + (size_t)(kb*128 + ct*16 + lr)*8);
      bf16x8 bn = *(const bf16x8*)(WTb + 73728 + (size_t)(kb*128 + 64 + ct*16 + lr)*8);
      aP[ct] = __builtin_amdgcn_mfma_f32_16x16x32_bf16(a, bp, aP[ct], 0, 0, 0);
      aN[ct] = __builtin_amdgcn_mfma_f32_16x16x32_bf16(a, bn, aN[ct], 0, 0, 0);
    }
  }
  // epilogue: gated residual (f32)
  float gt = gate[0], og = 1.0f - gt;
  #pragma unroll
  for (int i = 0; i < 4; ++i){
    int node = base_row + 4*q + i;
    if (node < NN){
      #pragma unroll
      for (int ct = 0; ct < 4; ++ct){
        int c = ct*16 + lr;
        out[(size_t)node*HH + c]      = gt*(aP[ct][i] + pb2[c])      + og*x0[(size_t)node*HH + c];
        out[(size_t)node*HH + 64 + c] = gt*(aN[ct][i] + pb2[64 + c]) + og*x0[(size_t)node*HH + 64 + c];
      }
    }
  }
}

// ---------------- launch ----------------

extern "C" void kernel_launch(void* const* d_in, const int* in_sizes, int n_in,
                              void* d_out, int out_size, void* d_ws, size_t ws_size,
                              hipStream_t stream){
  (void)in_sizes; (void)n_in; (void)out_size;
  const float* x     = (const float*)d_in[0];
  const int*   pe    = (const int*)d_in[1];
  const int*   ne    = (const int*)d_in[2];
  const float* c0_pl = (const float*)d_in[3];
  const float* c0_pr = (const float*)d_in[4];
  const float* c0_pr_b = (const float*)d_in[5];
  const float* c0_nl = (const float*)d_in[6];
  const float* c0_nr = (const float*)d_in[7];
  const float* c0_nr_b = (const float*)d_in[8];
  const float* c1_pl = (const float*)d_in[9];
  const float* c1_pr = (const float*)d_in[10];
  const float* c1_pr_b = (const float*)d_in[11];
  const float* c1_nl = (const float*)d_in[12];
  const float* c1_nr = (const float*)d_in[13];
  const float* c1_nr_b = (const float*)d_in[14];
  const float* ln0_g = (const float*)d_in[15];
  const float* ln0_b = (const float*)d_in[16];
  const float* ln1_g = (const float*)d_in[17];
  const float* ln1_b = (const float*)d_in[18];
  const float* pw1   = (const float*)d_in[19];
  const float* pb1   = (const float*)d_in[20];
  const float* pw2   = (const float*)d_in[21];
  const float* pb2   = (const float*)d_in[22];
  const float* gate  = (const float*)d_in[23];
  float* out = (float*)d_out;

  // Workspace layout (all bf16 activations). h1 aliases s_pos (wave-local rows).
  short* x_bf  = (short*)d_ws;                         // NN*HH bf16
  short* s_pos = x_bf + (size_t)NN * HH;               // NN*HH (then h1)
  short* s_neg = s_pos + (size_t)NN * HH;              // NN*HH
  short* h0    = s_neg + (size_t)NN * HH;              // NN*HH
  float* rp    = (float*)(h0 + (size_t)NN * HH);       // N
  float* rn    = rp + NN;                              // N
  short* WTb   = (short*)(rn + NN);                    // 90112 bf16 (16B-aligned)
  int* cnt_p = (int*)(WTb + 90112);                    // N
  int* cnt_n = cnt_p + NN;                             // N
  int* off_p = cnt_n + NN;                             // N+1
  int* off_n = off_p + NN + 1;                         // N+1
  int* cur_p = off_n + NN + 1;                         // N
  int* cur_n = cur_p + NN;                             // N
  int* parts = cur_n + NN;                             // 256
  int* srcp  = parts + 256;                            // E
  int* srcn  = srcp + EE;                              // E
  const size_t need = (size_t)((char*)(srcn + EE) - (char*)d_ws);
  if (ws_size < need) return;  // defensive: never scribble OOB

  hipMemsetAsync(cnt_p, 0, (size_t)2 * NN * sizeof(int), stream);
  cvt_kernel<<<(NN * HH / 8 + 255) / 256, 256, 0, stream>>>(x, x_bf);
  prep_kernel<<<352, 256, 0, stream>>>(c0_pl, c0_pr, c0_nl, c0_nr,
                                       c1_pl, c1_pr, c1_nl, c1_nr, pw1, pw2, WTb);
  hist_kernel<<<(2 * EE) / 256, 256, 0, stream>>>(pe, ne, cnt_p, cnt_n);
  scan1_kernel<<<dim3(98, 2), 256, 0, stream>>>(cnt_p, cnt_n, off_p, off_n, parts);
  scan2_kernel<<<1, 64, 0, stream>>>(parts);
  scan3_kernel<<<dim3(391, 2), 256, 0, stream>>>(parts, cnt_p, cnt_n, off_p, off_n,
                                                 cur_p, cur_n, rp, rn);
  scatter_kernel<<<(2 * EE) / 256, 256, 0, stream>>>(pe, ne, cur_p, cur_n, srcp, srcn);

  // layer 0
  agg_gather_kernel<<<(2 * NN * 64) / 256, 256, 0, stream>>>(x_bf, srcp, srcn, off_p, off_n,
                                                             rp, rn, s_pos, s_neg);
  l0_kernel<<<(NN + 63) / 64, 256, 0, stream>>>(x_bf, s_pos, s_neg, WTb,
                                                c0_pr_b, c0_nr_b, ln0_g, ln0_b, h0);
  // layer 1 (reuse CSR; h0 is 25.6 MB bf16 -> L3-resident gather)
  agg_gather_kernel<<<(2 * NN * 64) / 256, 256, 0, stream>>>(h0, srcp, srcn, off_p, off_n,
                                                             rp, rn, s_pos, s_neg);
  l1_kernel<<<(NN + 63) / 64, 256, 0, stream>>>(h0, s_pos, s_neg, WTb,
                                                c1_pr_b, c1_nr_b, ln1_g, ln1_b, s_pos /*h1*/);
  // MLP + gated residual
  mlp_kernel<<<(NN + 63) / 64, 256, 0, stream>>>(s_pos /*h1*/, x, WTb, pb1, pb2, gate, out);
}